// Round 14
// baseline (226.546 us; speedup 1.0000x reference)
//
#include <hip/hip_runtime.h>
#include <math.h>

#define NB 64
#define NT 256
#define NS 64
#define ND0 320
#define ND1 960
#define ND2 2880
#define NH 2
#define DC 704    // compact h width: [x(64) | A00x(64) | P00(256) | A01x(64) | P01(256)]
#define GP 1024   // padded per-head G width for layer 1

typedef __attribute__((ext_vector_type(8))) _Float16 f16x8;
typedef __attribute__((ext_vector_type(4))) float f32x4;
typedef __attribute__((ext_vector_type(4))) short short4v;

typedef const __attribute__((address_space(1))) void* gas_ptr;
typedef __attribute__((address_space(3))) void* las_ptr;
#define GLOAD16(g, l) __builtin_amdgcn_global_load_lds((gas_ptr)(g), (las_ptr)(l), 16, 0, 0)
#define MFMAH(a, b, c) __builtin_amdgcn_mfma_f32_16x16x32_f16((a), (b), (c), 0, 0, 0)

__device__ __forceinline__ short f2h(float v) {
    union { _Float16 h; short s; } u; u.h = (_Float16)v; return u.s;
}
__device__ __forceinline__ float h2f(short b) {
    union { _Float16 h; short s; } u; u.s = b; return (float)u.h;
}
__device__ __forceinline__ int swz(int o) { return o ^ (((o >> 7) & 7) << 4); }    // 128B rows

// ================= fused causal score + softmax (tile 128x256) =================
// S[t,s] = sum_k A[t,k]*B[s,k] + G[t,64+s];  P[t,s] = softmax_s(S) as fp16.
// LAYER 0: K=64. LAYER 1: K=704 with AJUMP (+256 col jump after first K-tile).
// grid (1, 2, NB*NH): by = row-half (m0 = by*128); zLo = batch, zHi = head.
// by=0 blocks skip the (fully masked) upper 128 columns' staging and MFMA.
template <int LAYER>
__global__ __launch_bounds__(256, 1) void score_sm(
    const short* __restrict__ G, int ldg, long sG, long hsG,   // A rows + gather bias
    const short* __restrict__ hc,                              // B rows (ld DC)
    short* __restrict__ pOut, int ldo, long sO, long hsO,
    int K)
{
    int by = blockIdx.y;
    int m0 = by * 128;
    long zLo = blockIdx.z & 63, zHi = blockIdx.z >> 6;
    const short* pAh = G + zLo * sG + zHi * hsG;
    const short* pBh = hc + zLo * 180224L;

    __shared__ short lds[24576];       // A 8192 | B-half0 8192 | B-half1 8192
    int tid = threadIdx.x;
    int lane = tid & 63, w = tid >> 6;
    int wr = w >> 1, wc = w & 1;       // wave tile 64(rows) x 128(cols)
    int q = lane >> 4, l15 = lane & 15;

    const short* aS[4]; const short* bS[8];
    int dLo[4];
#pragma unroll
    for (int j = 0; j < 4; ++j) {
        int o = j * 4096 + tid * 16;
        int c = swz(o); int r = c >> 7, col = (c & 127) >> 1;
        dLo[j] = o >> 1;
        aS[j] = pAh + (long)(m0 + r) * ldg + col;
        bS[j] = pBh + (long)r * DC + col;
        bS[j + 4] = pBh + (long)(128 + r) * DC + col;
    }

    int oa[4][2], ob[8][2];
#pragma unroll
    for (int mf = 0; mf < 4; ++mf)
#pragma unroll
        for (int kf = 0; kf < 2; ++kf) {
            int row = wr * 64 + mf * 16 + l15;
            oa[mf][kf] = swz(row * 128 + (kf * 32 + (q << 3)) * 2) >> 1;
        }
#pragma unroll
    for (int nf = 0; nf < 8; ++nf)
#pragma unroll
        for (int kf = 0; kf < 2; ++kf) {
            int s = wc * 128 + nf * 16 + l15;
            int half = s >> 7, sr = s & 127;
            ob[nf][kf] = half * 8192 + (swz(sr * 128 + (kf * 32 + (q << 3)) * 2) >> 1);
        }

    f32x4 acc[4][8] = {};

    for (int k0 = 0; k0 < K; k0 += 64) {
        int step = (LAYER == 1 && k0 == 0) ? 320 : 64;
#pragma unroll
        for (int j = 0; j < 4; ++j) {
            GLOAD16(aS[j], lds + dLo[j]);
            aS[j] += step;
            GLOAD16(bS[j], lds + 8192 + dLo[j]);
            bS[j] += 64;
        }
        if (by) {
#pragma unroll
            for (int j = 0; j < 4; ++j) {
                GLOAD16(bS[j + 4], lds + 16384 + dLo[j]);
                bS[j + 4] += 64;
            }
        }
        __syncthreads();
        if (by || wc == 0) {           // wave-uniform: by=0 upper-col waves idle
#pragma unroll
            for (int kf = 0; kf < 2; ++kf) {
                f16x8 vb[8];
#pragma unroll
                for (int nf = 0; nf < 8; ++nf)
                    vb[nf] = *(const f16x8*)(lds + 8192 + ob[nf][kf]);
#pragma unroll
                for (int mf = 0; mf < 4; ++mf) {
                    f16x8 va = *(const f16x8*)(lds + oa[mf][kf]);
#pragma unroll
                    for (int nf = 0; nf < 8; ++nf)
                        acc[mf][nf] = MFMAH(va, vb[nf], acc[mf][nf]);
                }
            }
        }
        __syncthreads();
    }

    // ---- epilogue: bias gather + causal mask + row softmax, write fp16 P ----
    float* red = (float*)lds;          // [0..255]: per-wc row max; [256..511]: row sum

    // bias + mask (in place)
#pragma unroll
    for (int mf = 0; mf < 4; ++mf)
#pragma unroll
        for (int nf = 0; nf < 8; ++nf) {
            int colb = wc * 128 + nf * 16 + l15;
#pragma unroll
            for (int rr = 0; rr < 4; ++rr) {
                int t = m0 + wr * 64 + mf * 16 + q * 4 + rr;
                if (colb <= t) {
                    long o = (zLo * 256 + t) * (long)ldg + 64 + colb + zHi * hsG;
                    acc[mf][nf][rr] += h2f(G[o]);
                } else {
                    acc[mf][nf][rr] = -1e30f;
                }
            }
        }

    // per-row max: over nf, then across the 16-lane col group
    float rmax[4][4];
#pragma unroll
    for (int mf = 0; mf < 4; ++mf)
#pragma unroll
        for (int rr = 0; rr < 4; ++rr) {
            float m = -1e30f;
#pragma unroll
            for (int nf = 0; nf < 8; ++nf) m = fmaxf(m, acc[mf][nf][rr]);
            m = fmaxf(m, __shfl_xor(m, 1));
            m = fmaxf(m, __shfl_xor(m, 2));
            m = fmaxf(m, __shfl_xor(m, 4));
            m = fmaxf(m, __shfl_xor(m, 8));
            rmax[mf][rr] = m;
        }
    if (l15 == 0) {
#pragma unroll
        for (int mf = 0; mf < 4; ++mf)
#pragma unroll
            for (int rr = 0; rr < 4; ++rr)
                red[wc * 128 + wr * 64 + mf * 16 + q * 4 + rr] = rmax[mf][rr];
    }
    __syncthreads();

    float fullm[4][4];
#pragma unroll
    for (int mf = 0; mf < 4; ++mf)
#pragma unroll
        for (int rr = 0; rr < 4; ++rr) {
            int row = wr * 64 + mf * 16 + q * 4 + rr;
            fullm[mf][rr] = fmaxf(red[row], red[128 + row]);
        }

    // exp + per-row sum
#pragma unroll
    for (int mf = 0; mf < 4; ++mf)
#pragma unroll
        for (int rr = 0; rr < 4; ++rr) {
            float s = 0.f;
#pragma unroll
            for (int nf = 0; nf < 8; ++nf) {
                float a = acc[mf][nf][rr];
                float e = (a > -1e29f) ? __expf(a - fullm[mf][rr]) : 0.f;
                acc[mf][nf][rr] = e;
                s += e;
            }
            s += __shfl_xor(s, 1);
            s += __shfl_xor(s, 2);
            s += __shfl_xor(s, 4);
            s += __shfl_xor(s, 8);
            rmax[mf][rr] = s;          // reuse as partial sum
        }
    if (l15 == 0) {
#pragma unroll
        for (int mf = 0; mf < 4; ++mf)
#pragma unroll
            for (int rr = 0; rr < 4; ++rr)
                red[256 + wc * 128 + wr * 64 + mf * 16 + q * 4 + rr] = rmax[mf][rr];
    }
    __syncthreads();

#pragma unroll
    for (int mf = 0; mf < 4; ++mf)
#pragma unroll
        for (int rr = 0; rr < 4; ++rr) {
            int row = wr * 64 + mf * 16 + q * 4 + rr;
            int t = m0 + row;
            float inv = 1.f / (red[256 + row] + red[256 + 128 + row]);
            long base = zLo * sO + zHi * hsO + (long)t * ldo;
#pragma unroll
            for (int nf = 0; nf < 8; ++nf) {
                int colb = wc * 128 + nf * 16 + l15;
                pOut[base + colb] = f2h(acc[mf][nf][rr] * inv);
            }
        }
}

// ================= 128x128 fp16 MFMA GEMM (G1) =================
// CMODE 1: G output -> fp16 Chi (ldch), bias = biasA1[head*921600 + (64+t)*960 + colh],
//          head=col>>10, colh=col&1023, skip colh>=960. SWZ: XCD-bijective 1D grid.
template <int CMODE, int TERMS, bool AJUMP, bool SWZ>
__global__ __launch_bounds__(256, 3) void gemm128(
    const short* Ah, int lda, long sA,
    const short* Bh, const short* Bl, int ldb, long sB,
    float* Cf, int ldcf, long sCf,
    short* Chi, int ldch,
    const short* biasH, long ldbias,
    const float* biasA1,
    long hsA, long hsC,
    int gx, int K)
{
    int bx, by;
    if (SWZ) {
        int wg = blockIdx.x;
        int q = gridDim.x >> 3;
        int sid = (wg & 7) * q + (wg >> 3);
        bx = sid % gx; by = sid / gx;
    } else { bx = blockIdx.x; by = blockIdx.y; }
    int m0 = by * 128, n0 = bx * 128;
    long zLo = blockIdx.z & 63, zHi = blockIdx.z >> 6;
    const short* pAh = Ah + zLo * sA + zHi * hsA;
    const short* pBh = Bh + zLo * sB;
    const short* pBl = (TERMS == 2) ? (Bl + zLo * sB) : nullptr;

    __shared__ short lds[8192 * (1 + TERMS)];  // A | Bh | [Bl]
    short* LAh = lds;
    short* LBh = lds + 8192;
    short* LBl = lds + 16384;

    int tid = threadIdx.x;
    int lane = tid & 63, w = tid >> 6;
    int wr = w >> 1, wc = w & 1;

    const short* aSH[4]; const short* bSH[4]; const short* bSL[4];
    int aLo[4], bLo[4];
#pragma unroll
    for (int j = 0; j < 4; ++j) {
        int o = j * 4096 + tid * 16;
        int c = swz(o); int r = c >> 7, col = (c & 127) >> 1;
        aSH[j] = pAh + (long)(m0 + r) * lda + col;
        aLo[j] = o >> 1;
        bSH[j] = pBh + (long)(n0 + r) * ldb + col;
        if (TERMS == 2) bSL[j] = pBl + (long)(n0 + r) * ldb + col;
        bLo[j] = o >> 1;
    }

    int oa[4][2], ob[4][2];
#pragma unroll
    for (int mf = 0; mf < 4; ++mf)
#pragma unroll
        for (int kf = 0; kf < 2; ++kf) {
            int row = wr * 64 + mf * 16 + (lane & 15);
            oa[mf][kf] = swz(row * 128 + (kf * 32 + ((lane >> 4) << 3)) * 2) >> 1;
        }
#pragma unroll
    for (int nf = 0; nf < 4; ++nf)
#pragma unroll
        for (int kf = 0; kf < 2; ++kf) {
            int row = wc * 64 + nf * 16 + (lane & 15);
            ob[nf][kf] = swz(row * 128 + (kf * 32 + ((lane >> 4) << 3)) * 2) >> 1;
        }

    f32x4 acc[4][4] = {};

    for (int k0 = 0; k0 < K; k0 += 64) {
        int step = (AJUMP && k0 == 0) ? 320 : 64;
#pragma unroll
        for (int j = 0; j < 4; ++j) {
            GLOAD16(aSH[j], LAh + aLo[j]);
            aSH[j] += step;
            GLOAD16(bSH[j], LBh + bLo[j]);
            bSH[j] += 64;
            if (TERMS == 2) { GLOAD16(bSL[j], LBl + bLo[j]); bSL[j] += 64; }
        }
        __syncthreads();
#pragma unroll
        for (int kf = 0; kf < 2; ++kf) {
            f16x8 vbh[4], vbl[4];
#pragma unroll
            for (int nf = 0; nf < 4; ++nf) {
                vbh[nf] = *(const f16x8*)(LBh + ob[nf][kf]);
                if (TERMS == 2) vbl[nf] = *(const f16x8*)(LBl + ob[nf][kf]);
            }
#pragma unroll
            for (int mf = 0; mf < 4; ++mf) {
                f16x8 vah = *(const f16x8*)(LAh + oa[mf][kf]);
#pragma unroll
                for (int nf = 0; nf < 4; ++nf) {
                    acc[mf][nf] = MFMAH(vah, vbh[nf], acc[mf][nf]);
                    if (TERMS == 2) acc[mf][nf] = MFMAH(vah, vbl[nf], acc[mf][nf]);
                }
            }
        }
        __syncthreads();
    }

#pragma unroll
    for (int mf = 0; mf < 4; ++mf)
#pragma unroll
        for (int nf = 0; nf < 4; ++nf) {
            f32x4 v = acc[mf][nf];
            int col  = n0 + wc * 64 + nf * 16 + (lane & 15);
            int rowb = m0 + wr * 64 + mf * 16 + ((lane >> 4) << 2);
            if (CMODE == 0) {
#pragma unroll
                for (int r = 0; r < 4; ++r)
                    Cf[zLo * sCf + zHi * hsC + (long)(rowb + r) * ldcf + col] = v[r];
            } else {
                int head = col >> 10, colh = col & 1023;
                if (colh < ND1) {
                    const float* bA = biasA1 + (long)head * 921600 + colh;
#pragma unroll
                    for (int r = 0; r < 4; ++r) {
                        int t = (rowb + r) & 255;
                        float f = v[r] + bA[(long)(64 + t) * 960];
                        Chi[(long)(rowb + r) * ldch + col] = f2h(f);
                    }
                }
            }
        }
}

// ================= 128x64 fp16 MFMA GEMM (small-N ops) =================
// BMODE: 0 none; 1 bias=biasF[zLo*hsBias+(64+t)*ldbias+col]; 3 OutU Wo pos fold
// BJUMP: B pointer jumps to head1 (UT stride 1048576) after k-tile 192.
template <int BMODE, int TERMS, bool KCAUSAL, bool ACC, bool OUTU, bool BJUMP>
__global__ __launch_bounds__(256) void gemm_mfma(
    const short* Ah, int lda, long sA,
    const short* Bh, const short* Bl, int ldb, long sB, long hsB,
    float* Cf, int ldcf, long sCf,
    short* Chi, short* Clo, int ldch, long sCh,
    const float* biasF, long ldbias, long hsBias,
    long hsA, long hsC,
    short* UThi,
    int K)
{
    int m0 = blockIdx.y * 128, n0 = blockIdx.x * 64;
    long zLo = blockIdx.z & 63, zHi = blockIdx.z >> 6;
    const short* pAh = Ah + zLo * sA + zHi * hsA;
    const short* pBh = Bh + zLo * sB + zHi * hsB;
    const short* pBl = (TERMS == 2) ? (Bl + zLo * sB + zHi * hsB) : nullptr;

    __shared__ short lds[8192 + TERMS * 4096]; // LAh 8192 | LBh 4096 | [LBl 4096]
    short* LAh = lds;
    short* LBh = lds + 8192;
    short* LBl = lds + 12288;

    int tid = threadIdx.x;
    int lane = tid & 63, w = tid >> 6;
    int wr = w >> 1, wc = w & 1;

    const short* aSH[4]; const short* bSH[2]; const short* bSL[2];
    int aLo[4], bLo[2];
#pragma unroll
    for (int j = 0; j < 4; ++j) {
        int o = j * 4096 + tid * 16;
        int c = swz(o); int r = c >> 7, col = (c & 127) >> 1;
        aSH[j] = pAh + (long)(m0 + r) * lda + col;
        aLo[j] = o >> 1;
    }
#pragma unroll
    for (int j = 0; j < 2; ++j) {
        int o = j * 4096 + tid * 16;
        int c = swz(o); int r = c >> 7, col = (c & 127) >> 1;
        bSH[j] = pBh + (long)(n0 + r) * ldb + col;
        if (TERMS == 2) bSL[j] = pBl + (long)(n0 + r) * ldb + col;
        bLo[j] = o >> 1;
    }

    int oa[4][2], ob[2][2];
#pragma unroll
    for (int mf = 0; mf < 4; ++mf)
#pragma unroll
        for (int kf = 0; kf < 2; ++kf) {
            int row = wr * 64 + mf * 16 + (lane & 15);
            oa[mf][kf] = swz(row * 128 + (kf * 32 + ((lane >> 4) << 3)) * 2) >> 1;
        }
#pragma unroll
    for (int nf = 0; nf < 2; ++nf)
#pragma unroll
        for (int kf = 0; kf < 2; ++kf) {
            int row = wc * 32 + nf * 16 + (lane & 15);
            ob[nf][kf] = swz(row * 128 + (kf * 32 + ((lane >> 4) << 3)) * 2) >> 1;
        }

    f32x4 acc[4][2] = {};
    int Klim = KCAUSAL ? (K < m0 + 128 ? K : m0 + 128) : K;

    for (int k0 = 0; k0 < Klim; k0 += 64) {
#pragma unroll
        for (int j = 0; j < 4; ++j) {
            GLOAD16(aSH[j], LAh + aLo[j]);
            aSH[j] += 64;
        }
        long bstep = (BJUMP && k0 == 192) ? (1048576L - 192L) : 64L;
#pragma unroll
        for (int j = 0; j < 2; ++j) {
            GLOAD16(bSH[j], LBh + bLo[j]);
            bSH[j] += bstep;
            if (TERMS == 2) { GLOAD16(bSL[j], LBl + bLo[j]); bSL[j] += bstep; }
        }
        __syncthreads();
#pragma unroll
        for (int kf = 0; kf < 2; ++kf) {
            f16x8 vbh[2], vbl[2];
#pragma unroll
            for (int nf = 0; nf < 2; ++nf) {
                vbh[nf] = *(const f16x8*)(LBh + ob[nf][kf]);
                if (TERMS == 2) vbl[nf] = *(const f16x8*)(LBl + ob[nf][kf]);
            }
#pragma unroll
            for (int mf = 0; mf < 4; ++mf) {
                f16x8 vah = *(const f16x8*)(LAh + oa[mf][kf]);
#pragma unroll
                for (int nf = 0; nf < 2; ++nf) {
                    acc[mf][nf] = MFMAH(vah, vbh[nf], acc[mf][nf]);
                    if (TERMS == 2) acc[mf][nf] = MFMAH(vah, vbl[nf], acc[mf][nf]);
                }
            }
        }
        __syncthreads();
    }

#pragma unroll
    for (int mf = 0; mf < 4; ++mf)
#pragma unroll
        for (int nf = 0; nf < 2; ++nf) {
            f32x4 v = acc[mf][nf];
            int col  = n0 + wc * 32 + nf * 16 + (lane & 15);
            int rowb = m0 + wr * 64 + mf * 16 + ((lane >> 4) << 2);
            if (BMODE == 1) {
#pragma unroll
                for (int r = 0; r < 4; ++r) {
                    int t = (rowb + r) & 255;
                    v[r] += biasF[zLo * hsBias + (long)(64 + t) * ldbias + col];
                }
            } else if (BMODE == 3) {
#pragma unroll
                for (int r = 0; r < 4; ++r) {
                    int t = (rowb + r) & 255;
                    v[r] += biasF[(long)(col - n0) * 2880 + (n0 >> 6) * 960 + 64 + t];
                }
            }
            if (OUTU) {
                if (n0 == 0) {
#pragma unroll
                    for (int r = 0; r < 4; ++r)
                        Cf[(long)(rowb + r) * ldcf + col] = v[r];
                } else {
                    int head = (n0 >> 6) - 1;
                    int o = col - n0;
                    short hs[4];
#pragma unroll
                    for (int r = 0; r < 4; ++r) hs[r] = f2h(v[r]);
                    short4v th = {hs[0], hs[1], hs[2], hs[3]};
                    *(short4v*)(UThi + head * 1048576L + (long)o * 16384 + rowb) = th;
                }
            } else if (ACC) {
#pragma unroll
                for (int r = 0; r < 4; ++r)
                    Cf[zLo * sCf + (long)(rowb + r) * ldcf + col] += v[r];
            } else if (Cf) {
#pragma unroll
                for (int r = 0; r < 4; ++r)
                    Cf[zLo * sCf + (long)(rowb + r) * ldcf + col] = v[r];
            } else {
#pragma unroll
                for (int r = 0; r < 4; ++r) {
                    float f = v[r];
                    short hi = f2h(f);
                    Chi[zHi * hsC + zLo * sCh + (long)(rowb + r) * ldch + col] = hi;
                    if (Clo)
                        Clo[zHi * hsC + zLo * sCh + (long)(rowb + r) * ldch + col] = f2h(f - h2f(hi));
                }
            }
        }
}

// ================= helpers =================
__global__ __launch_bounds__(256) void build_h_rows(const float* __restrict__ x,
                                                    short* __restrict__ hhi) {
    int idx = blockIdx.x * 256 + threadIdx.x;
    int bt = idx >> 6, c = idx & 63;
    hhi[(long)bt * DC + c] = f2h(x[(long)bt * NS + c]);
}

__global__ __launch_bounds__(256) void build_hT_x(const float* __restrict__ x,
                                                  short* __restrict__ hTh,
                                                  short* __restrict__ hTl) {
    __shared__ float tile[32][33];
    int c0 = blockIdx.x * 32, t0 = blockIdx.y * 32, b = blockIdx.z;
    int tx = threadIdx.x, ty = threadIdx.y;
    const float* xb = x + (long)b * NT * NS;
#pragma unroll
    for (int i = ty; i < 32; i += 8) tile[i][tx] = xb[(long)(t0 + i) * NS + c0 + tx];
    __syncthreads();
    long base = (long)b * (NS * 256);
#pragma unroll
    for (int i = ty; i < 32; i += 8) {
        float v = tile[tx][i];
        short hi = f2h(v);
        hTh[base + (long)(c0 + i) * 256 + t0 + tx] = hi;
        hTl[base + (long)(c0 + i) * 256 + t0 + tx] = f2h(v - h2f(hi));
    }
}

__global__ void build_At(const float* __restrict__ A,
                         short* __restrict__ hi, short* __restrict__ lo,
                         int dN, int dK, int srcLd, int shift, int dSrcN) {
    __shared__ float tile[32][33];
    int k0 = blockIdx.x * 32, n0 = blockIdx.y * 32;
    long hbase = (long)blockIdx.z * srcLd * srcLd;
    int tx = threadIdx.x, ty = threadIdx.y;
#pragma unroll
    for (int i = ty; i < 32; i += 8) {
        int k = k0 + i;
        int srck = (k < 64) ? k : k + shift;
        tile[i][tx] = (n0 + tx < dSrcN) ? A[hbase + (long)srck * srcLd + n0 + tx] : 0.f;
    }
    __syncthreads();
    long obase = (long)blockIdx.z * dN * dK;
#pragma unroll
    for (int i = ty; i < 32; i += 8) {
        float v = tile[tx][i];
        short h = f2h(v);
        hi[obase + (long)(n0 + i) * dK + k0 + tx] = h;
        if (lo) lo[obase + (long)(n0 + i) * dK + k0 + tx] = f2h(v - h2f(h));
    }
}

__global__ __launch_bounds__(256) void build_Wf(const float* __restrict__ Wo,
                                                short* __restrict__ hi) {
    int idx = blockIdx.x * 256 + threadIdx.x;
    if (idx >= 192 * DC) return;
    int r = idx / DC, kc = idx - r * DC;
    int o = r & 63, chunk = r >> 6;
    int srck = (kc < 64) ? kc : kc + 256;
    hi[idx] = f2h(Wo[(long)o * ND2 + chunk * 960 + srck]);
}

// ================= fp32 fallback (round-1, known-good) =================
__global__ __launch_bounds__(256) void build_h0(const float* __restrict__ x,
                                                float* __restrict__ h) {
    int idx = blockIdx.x * 256 + threadIdx.x;
    int bt = idx / ND0;
    int c  = idx - bt * ND0;
    int t  = bt & (NT - 1);
    float v;
    if (c < NS) v = x[(long)bt * NS + c];
    else        v = ((c - NS) == t) ? 1.0f : 0.0f;
    h[(long)bt * ND2 + c] = v;
}

template <bool BT, bool CAUSAL>
__global__ __launch_bounds__(256) void gemm64(
    const float* __restrict__ A, int lda, long sA,
    const float* __restrict__ Bm, int ldb, long sB,
    float* __restrict__ C, int ldc, long sC, int K)
{
    int m0 = blockIdx.y * 64, n0 = blockIdx.x * 64;
    if (CAUSAL && n0 > m0 + 63) return;
    long z = blockIdx.z;
    A += z * sA; Bm += z * sB; C += z * sC;

    __shared__ float As[16][68];
    __shared__ float Bs[16][68];

    int tid = threadIdx.x;
    int tx = tid & 15, ty = tid >> 4;
    int rowA = tid >> 2, kA = (tid & 3) << 2;
    int kB = tid >> 4,  colB = (tid & 15) << 2;

    float acc[4][4] = {};

    for (int k0 = 0; k0 < K; k0 += 16) {
        float4 av = *(const float4*)(A + (long)(m0 + rowA) * lda + k0 + kA);
        As[kA + 0][rowA] = av.x; As[kA + 1][rowA] = av.y;
        As[kA + 2][rowA] = av.z; As[kA + 3][rowA] = av.w;
        if (BT) {
            float4 bv = *(const float4*)(Bm + (long)(n0 + rowA) * ldb + k0 + kA);
            Bs[kA + 0][rowA] = bv.x; Bs[kA + 1][rowA] = bv.y;
            Bs[kA + 2][rowA] = bv.z; Bs[kA + 3][rowA] = bv.w;
        } else {
            float4 bv = *(const float4*)(Bm + (long)(k0 + kB) * ldb + n0 + colB);
            *(float4*)(&Bs[kB][colB]) = bv;
        }
        __syncthreads();
#pragma unroll
        for (int kk = 0; kk < 16; ++kk) {
            float4 a4 = *(const float4*)(&As[kk][ty << 2]);
            float4 b4 = *(const float4*)(&Bs[kk][tx << 2]);
            float a[4] = {a4.x, a4.y, a4.z, a4.w};
            float b[4] = {b4.x, b4.y, b4.z, b4.w};
#pragma unroll
            for (int i = 0; i < 4; ++i)
#pragma unroll
                for (int j = 0; j < 4; ++j)
                    acc[i][j] += a[i] * b[j];
        }
        __syncthreads();
    }
#pragma unroll
    for (int i = 0; i < 4; ++i) {
        float4 v = {acc[i][0], acc[i][1], acc[i][2], acc[i][3]};
        *(float4*)(C + (long)(m0 + (ty << 2) + i) * ldc + n0 + (tx << 2)) = v;
    }
}

__global__ __launch_bounds__(256) void softmax_causal(float* __restrict__ P) {
    int row  = blockIdx.x * 4 + (threadIdx.x >> 6);
    int t    = row & (NT - 1);
    int lane = threadIdx.x & 63;
    int s0   = lane << 2;
    float* p = P + (long)row * NT;

    float4 v = *(const float4*)(p + s0);
    float vv[4] = {v.x, v.y, v.z, v.w};
    float mx = -INFINITY;
#pragma unroll
    for (int j = 0; j < 4; ++j)
        if (s0 + j <= t) mx = fmaxf(mx, vv[j]);
    for (int off = 32; off; off >>= 1) mx = fmaxf(mx, __shfl_down(mx, off));
    mx = __shfl(mx, 0);

    float e[4]; float sum = 0.f;
#pragma unroll
    for (int j = 0; j < 4; ++j) {
        e[j] = (s0 + j <= t) ? __expf(vv[j] - mx) : 0.f;
        sum += e[j];
    }
    for (int off = 32; off; off >>= 1) sum += __shfl_down(sum, off);
    sum = __shfl(sum, 0);
    float inv = 1.f / sum;
    float4 o = {e[0] * inv, e[1] * inv, e[2] * inv, e[3] * inv};
    *(float4*)(p + s0) = o;
}

// ================= launch =================
extern "C" void kernel_launch(void* const* d_in, const int* in_sizes, int n_in,
                              void* d_out, int out_size, void* d_ws, size_t ws_size,
                              hipStream_t stream) {
    const float* x  = (const float*)d_in[0];
    const float* A0 = (const float*)d_in[1];
    const float* A1 = (const float*)d_in[2];
    const float* Wo = (const float*)d_in[3];
    float* out = (float*)d_out;

    if (ws_size >= 175120384UL) {
        char* wsb = (char*)d_ws;
        short* hc_hi = (short*)(wsb);                    // [16384][704]
        short* G_hi  = (short*)(wsb + 46137344L);        // [16384][2048]
        short* P     = (short*)(wsb + 146800640L);       // [16384][512] both-head P
        short* hT_hi = (short*)(wsb + 163577856L);       // [64][64][256]
        short* hT_lo = (short*)(wsb + 165675008L);
        short* At_hi = (short*)(wsb + 167772160L);       // [2][1024][704]
        short* Wf_hi = (short*)(wsb + 170655744L);       // [192][704]
        short* UT_hi = (short*)(wsb + 170926080L);       // [2][64][16384], end 175120384

        build_h_rows<<<4096, 256, 0, stream>>>(x, hc_hi);
        build_hT_x<<<dim3(2, 8, 64), dim3(32, 8), 0, stream>>>(x, hT_hi, hT_lo);
        build_Wf<<<528, 256, 0, stream>>>(Wo, Wf_hi);

        // -------- layer 0 (K=64 after pos-fold) --------
        build_At<<<dim3(2, 10, 2), dim3(32, 8), 0, stream>>>(A0, At_hi, nullptr, ND0, 64, ND0, 0, ND0);
        // G0 = x @ A0^T + A0[64+t,:] -> G_hi [16384][640], both heads (z=2: zLo=head)
        gemm_mfma<1, 1, false, false, false, false><<<dim3(5, 128, 2), 256, 0, stream>>>(
            hc_hi, DC, 0L,
            At_hi, nullptr, 64, 20480L, 0L,
            nullptr, 0, 0L, G_hi, nullptr, 640, 320L,
            A0, 320L, 102400L,
            0L, 0L,
            nullptr, 64);
        // fused score+softmax L0: P -> hc cols [128 + head*320]
        score_sm<0><<<dim3(1, 2, 128), 256, 0, stream>>>(
            G_hi, 640, 163840L, 320L,
            hc_hi,
            hc_hi + 128, DC, 180224L, 320L,
            64);
        // PV0: hc[., 64+head*320 ..] = P @ x  (both heads, z=128), 2-term B
        gemm_mfma<0, 2, true, false, false, false><<<dim3(1, 2, 128), 256, 0, stream>>>(
            hc_hi + 128, DC, 180224L,
            hT_hi, hT_lo, 256, 16384L, 0L,
            nullptr, 0, 0L,
            hc_hi + 64, nullptr, DC, 180224L,
            nullptr, 0L, 0L,
            320L, 320L,
            nullptr, 256);

        // -------- fused out-base + U heads (N=192, 1-term, U hi-only) --------
        gemm_mfma<3, 1, false, false, true, false><<<dim3(3, 128, 1), 256, 0, stream>>>(
            hc_hi, DC, 0L,
            Wf_hi, nullptr, DC, 0L, 0L,
            out, NS, 0L, nullptr, nullptr, 0, 0L,
            Wo, 0L, 0L,
            0L, 0L,
            UT_hi, DC);

        // -------- layer 1 --------
        build_At<<<dim3(22, 32, 2), dim3(32, 8), 0, stream>>>(A1, At_hi, nullptr, GP, DC, ND1, 256, ND1);
        // G1 = hc @ At^T + pos bias: 128x128 kernel, both heads (N=2048), XCD swizzle
        gemm128<1, 1, false, true><<<dim3(2048, 1, 1), 256, 0, stream>>>(
            hc_hi, DC, 0L,
            At_hi, nullptr, DC, 0L,
            nullptr, 0, 0L,
            G_hi, 2048,
            nullptr, 0L,
            A1,
            0L, 0L, 16, DC);
        // fused score+softmax L1 (AJUMP compact K=704): P -> [16384][512] head-packed
        score_sm<1><<<dim3(1, 2, 128), 256, 0, stream>>>(
            G_hi, 2048, 524288L, 1024L,
            hc_hi,
            P, 512, 131072L, 256L,
            DC);
        // out += [P0|P1] @ [U0;U1]^T  (single dispatch, K=512, BJUMP at k=192->head1)
        gemm_mfma<0, 1, false, true, false, true><<<dim3(1, 2, 64), 256, 0, stream>>>(
            P, 512, 131072L,
            UT_hi, nullptr, 16384, 256L, 0L,
            out, NS, 16384L, nullptr, nullptr, 0, 0L,
            nullptr, 0L, 0L,
            0L, 0L,
            nullptr, 512);
        return;
    }

    // ---------- fp32 fallback ----------
    float* ws = (float*)d_ws;
    float* h  = ws;
    float* G  = ws + 47185920L;
    float* Pf = ws + 47185920L + 15728640L;

    build_h0<<<(NB * NT * ND0) / 256, 256, 0, stream>>>(x, h);

    for (int layer = 0; layer < 2; ++layer) {
        int d = layer ? ND1 : ND0;
        const float* Am = layer ? A1 : A0;
        for (int head = 0; head < NH; ++head) {
            const float* Ah = Am + (long)head * d * d;
            gemm64<false, false><<<dim3(d / 64, 256, 1), 256, 0, stream>>>(
                h, ND2, 0L, Ah, d, 0L, G, d, 0L, d);
            gemm64<true, true><<<dim3(4, 4, NB), 256, 0, stream>>>(
                G, d, (long)NT * d, h, ND2, (long)NT * ND2,
                Pf, NT, (long)NT * NT, d);
            softmax_causal<<<(NB * NT) / 4, 256, 0, stream>>>(Pf);
            gemm64<false, false><<<dim3(d / 64, 4, NB), 256, 0, stream>>>(
                Pf, NT, (long)NT * NT, h, ND2, (long)NT * ND2,
                h + (long)d * (1 + head), ND2, (long)NT * ND2, NT);
        }
    }
    gemm64<true, false><<<dim3(1, 256, 1), 256, 0, stream>>>(
        h, ND2, 0L, Wo, ND2, 0L, out, NS, 0L, ND2);
}

// Round 15
// 177.542 us; speedup vs baseline: 1.2760x; 1.2760x over previous
//
#include <hip/hip_runtime.h>
#include <math.h>

#define NB 64
#define NT 256
#define NS 64
#define ND0 320
#define ND1 960
#define ND2 2880
#define NH 2
#define DC 704    // compact h width: [x(64) | A00x(64) | P00(256) | A01x(64) | P01(256)]

typedef __attribute__((ext_vector_type(8))) _Float16 f16x8;
typedef __attribute__((ext_vector_type(4))) float f32x4;
typedef __attribute__((ext_vector_type(4))) short short4v;

typedef const __attribute__((address_space(1))) void* gas_ptr;
typedef __attribute__((address_space(3))) void* las_ptr;
#define GLOAD16(g, l) __builtin_amdgcn_global_load_lds((gas_ptr)(g), (las_ptr)(l), 16, 0, 0)
#define MFMAH(a, b, c) __builtin_amdgcn_mfma_f32_16x16x32_f16((a), (b), (c), 0, 0, 0)

__device__ __forceinline__ short f2h(float v) {
    union { _Float16 h; short s; } u; u.h = (_Float16)v; return u.s;
}
__device__ __forceinline__ float h2f(short b) {
    union { _Float16 h; short s; } u; u.s = b; return (float)u.h;
}
__device__ __forceinline__ int swz(int o) { return o ^ (((o >> 7) & 7) << 4); }    // 128B rows

// ================= G1 kernel: 256x128 fp16 GEMM, N=1920 unpadded =================
// G[m, col] = sum_k hc[m,k]*At[col,k] + A1[head][64+(m&255)][colh],
// head = col>=960, colh = col - head*960. Tile 256(M) x 128(N), BK=64, 11 K-tiles.
// 4 waves (2Mx2N), wave tile 128x64. LDS: A 32KB | B 16KB. XCD-bijective 1D grid (960).
__global__ __launch_bounds__(256, 2) void gemmG1(
    const short* __restrict__ hc,
    const short* __restrict__ At,
    short* __restrict__ G,
    const float* __restrict__ A1)
{
    int wg = blockIdx.x;
    int q8 = gridDim.x >> 3;           // 120
    int sid = (wg & 7) * q8 + (wg >> 3);
    int bx = sid % 15, by = sid / 15;
    int m0 = by << 8, n0 = bx << 7;

    __shared__ short lds[24576];       // A 16384 shorts | B 8192 shorts
    int tid = threadIdx.x;
    int lane = tid & 63, w = tid >> 6;
    int wm = w >> 1, wn = w & 1;
    int q = lane >> 4, l15 = lane & 15;

    const short* aS[8]; const short* bS[4];
    int dA[8], dB[4];
#pragma unroll
    for (int j = 0; j < 8; ++j) {
        int o = j * 4096 + tid * 16;
        int c = swz(o); int r = c >> 7, col = (c & 127) >> 1;
        aS[j] = hc + (long)(m0 + r) * DC + col;
        dA[j] = o >> 1;
    }
#pragma unroll
    for (int j = 0; j < 4; ++j) {
        int o = j * 4096 + tid * 16;
        int c = swz(o); int r = c >> 7, col = (c & 127) >> 1;
        bS[j] = At + (long)(n0 + r) * DC + col;
        dB[j] = o >> 1;
    }

    int oa[8][2], ob[4][2];
#pragma unroll
    for (int mf = 0; mf < 8; ++mf)
#pragma unroll
        for (int kf = 0; kf < 2; ++kf) {
            int row = wm * 128 + mf * 16 + l15;
            oa[mf][kf] = swz(row * 128 + (kf * 32 + (q << 3)) * 2) >> 1;
        }
#pragma unroll
    for (int nf = 0; nf < 4; ++nf)
#pragma unroll
        for (int kf = 0; kf < 2; ++kf) {
            int row = wn * 64 + nf * 16 + l15;
            ob[nf][kf] = swz(row * 128 + (kf * 32 + (q << 3)) * 2) >> 1;
        }

    f32x4 acc[8][4] = {};

    for (int k0 = 0; k0 < DC; k0 += 64) {
#pragma unroll
        for (int j = 0; j < 8; ++j) { GLOAD16(aS[j], lds + dA[j]); aS[j] += 64; }
#pragma unroll
        for (int j = 0; j < 4; ++j) { GLOAD16(bS[j], lds + 16384 + dB[j]); bS[j] += 64; }
        __syncthreads();
#pragma unroll
        for (int kf = 0; kf < 2; ++kf) {
            f16x8 vb[4];
#pragma unroll
            for (int nf = 0; nf < 4; ++nf)
                vb[nf] = *(const f16x8*)(lds + 16384 + ob[nf][kf]);
#pragma unroll
            for (int mf = 0; mf < 8; ++mf) {
                f16x8 va = *(const f16x8*)(lds + oa[mf][kf]);
#pragma unroll
                for (int nf = 0; nf < 4; ++nf)
                    acc[mf][nf] = MFMAH(va, vb[nf], acc[mf][nf]);
            }
        }
        __syncthreads();
    }

#pragma unroll
    for (int mf = 0; mf < 8; ++mf)
#pragma unroll
        for (int nf = 0; nf < 4; ++nf) {
            int col = n0 + wn * 64 + nf * 16 + l15;
            int head = (col >= 960) ? 1 : 0;
            int colh = col - head * 960;
            const float* bA = A1 + (long)head * 921600 + colh;
            int rowb = m0 + wm * 128 + mf * 16 + (q << 2);
#pragma unroll
            for (int r = 0; r < 4; ++r) {
                int t = (rowb + r) & 255;
                float f = acc[mf][nf][r] + bA[(long)(64 + t) * 960];
                G[(long)(rowb + r) * 1920 + col] = f2h(f);
            }
        }
}

// ================= 128x128 fp16 MFMA GEMM (scores) =================
// CMODE 0: causal scores -> fp32 Cf + gather bias biasH[(zLo*256+row)*ldbias+64+col+zHi*hsA]
// AJUMP: A cols jump +256 after first K-step.
template <int CMODE, int TERMS, bool AJUMP>
__global__ __launch_bounds__(256, 3) void gemm128(
    const short* Ah, int lda, long sA,
    const short* Bh, const short* Bl, int ldb, long sB,
    float* Cf, int ldcf, long sCf,
    const short* biasH, long ldbias,
    long hsA, long hsC,
    int K)
{
    int bx = blockIdx.x, by = blockIdx.y;
    int m0 = by * 128, n0 = bx * 128;
    if (CMODE == 0 && n0 > m0 + 127) return;   // causal tile skip
    long zLo = blockIdx.z & 63, zHi = blockIdx.z >> 6;
    const short* pAh = Ah + zLo * sA + zHi * hsA;
    const short* pBh = Bh + zLo * sB;
    const short* pBl = (TERMS == 2) ? (Bl + zLo * sB) : nullptr;

    __shared__ short lds[8192 * (1 + TERMS)];  // A | Bh | [Bl]
    short* LAh = lds;
    short* LBh = lds + 8192;
    short* LBl = lds + 16384;

    int tid = threadIdx.x;
    int lane = tid & 63, w = tid >> 6;
    int wr = w >> 1, wc = w & 1;

    const short* aSH[4]; const short* bSH[4]; const short* bSL[4];
    int aLo[4], bLo[4];
#pragma unroll
    for (int j = 0; j < 4; ++j) {
        int o = j * 4096 + tid * 16;
        int c = swz(o); int r = c >> 7, col = (c & 127) >> 1;
        aSH[j] = pAh + (long)(m0 + r) * lda + col;
        aLo[j] = o >> 1;
        bSH[j] = pBh + (long)(n0 + r) * ldb + col;
        if (TERMS == 2) bSL[j] = pBl + (long)(n0 + r) * ldb + col;
        bLo[j] = o >> 1;
    }

    int oa[4][2], ob[4][2];
#pragma unroll
    for (int mf = 0; mf < 4; ++mf)
#pragma unroll
        for (int kf = 0; kf < 2; ++kf) {
            int row = wr * 64 + mf * 16 + (lane & 15);
            oa[mf][kf] = swz(row * 128 + (kf * 32 + ((lane >> 4) << 3)) * 2) >> 1;
        }
#pragma unroll
    for (int nf = 0; nf < 4; ++nf)
#pragma unroll
        for (int kf = 0; kf < 2; ++kf) {
            int row = wc * 64 + nf * 16 + (lane & 15);
            ob[nf][kf] = swz(row * 128 + (kf * 32 + ((lane >> 4) << 3)) * 2) >> 1;
        }

    f32x4 acc[4][4] = {};

    for (int k0 = 0; k0 < K; k0 += 64) {
        int step = (AJUMP && k0 == 0) ? 320 : 64;
#pragma unroll
        for (int j = 0; j < 4; ++j) {
            GLOAD16(aSH[j], LAh + aLo[j]);
            aSH[j] += step;
            GLOAD16(bSH[j], LBh + bLo[j]);
            bSH[j] += 64;
            if (TERMS == 2) { GLOAD16(bSL[j], LBl + bLo[j]); bSL[j] += 64; }
        }
        __syncthreads();
#pragma unroll
        for (int kf = 0; kf < 2; ++kf) {
            f16x8 vbh[4], vbl[4];
#pragma unroll
            for (int nf = 0; nf < 4; ++nf) {
                vbh[nf] = *(const f16x8*)(LBh + ob[nf][kf]);
                if (TERMS == 2) vbl[nf] = *(const f16x8*)(LBl + ob[nf][kf]);
            }
#pragma unroll
            for (int mf = 0; mf < 4; ++mf) {
                f16x8 vah = *(const f16x8*)(LAh + oa[mf][kf]);
#pragma unroll
                for (int nf = 0; nf < 4; ++nf) {
                    acc[mf][nf] = MFMAH(vah, vbh[nf], acc[mf][nf]);
                    if (TERMS == 2) acc[mf][nf] = MFMAH(vah, vbl[nf], acc[mf][nf]);
                }
            }
        }
        __syncthreads();
    }

#pragma unroll
    for (int mf = 0; mf < 4; ++mf)
#pragma unroll
        for (int nf = 0; nf < 4; ++nf) {
            f32x4 v = acc[mf][nf];
            int col  = n0 + wc * 64 + nf * 16 + (lane & 15);
            int rowb = m0 + wr * 64 + mf * 16 + ((lane >> 4) << 2);
#pragma unroll
            for (int r = 0; r < 4; ++r) {
                long o = (zLo * 256 + rowb + r) * ldbias + 64 + col + zHi * hsA;
                v[r] += h2f(biasH[o]);
            }
#pragma unroll
            for (int r = 0; r < 4; ++r)
                Cf[zLo * sCf + zHi * hsC + (long)(rowb + r) * ldcf + col] = v[r];
        }
}

// ================= 128x64 fp16 MFMA GEMM (small-N ops) =================
// BMODE: 0 none; 1 bias=biasF[zLo*hsBias+(64+t)*ldbias+col]; 3 OutU Wo pos fold
// BJUMP: B pointer jumps to head1 (UT stride 1048576) after k-tile 192.
template <int BMODE, int TERMS, bool KCAUSAL, bool ACC, bool OUTU, bool BJUMP>
__global__ __launch_bounds__(256) void gemm_mfma(
    const short* Ah, int lda, long sA,
    const short* Bh, const short* Bl, int ldb, long sB, long hsB,
    float* Cf, int ldcf, long sCf,
    short* Chi, short* Clo, int ldch, long sCh,
    const float* biasF, long ldbias, long hsBias,
    long hsA, long hsC,
    short* UThi,
    int K)
{
    int m0 = blockIdx.y * 128, n0 = blockIdx.x * 64;
    long zLo = blockIdx.z & 63, zHi = blockIdx.z >> 6;
    const short* pAh = Ah + zLo * sA + zHi * hsA;
    const short* pBh = Bh + zLo * sB + zHi * hsB;
    const short* pBl = (TERMS == 2) ? (Bl + zLo * sB + zHi * hsB) : nullptr;

    __shared__ short lds[8192 + TERMS * 4096]; // LAh 8192 | LBh 4096 | [LBl 4096]
    short* LAh = lds;
    short* LBh = lds + 8192;
    short* LBl = lds + 12288;

    int tid = threadIdx.x;
    int lane = tid & 63, w = tid >> 6;
    int wr = w >> 1, wc = w & 1;

    const short* aSH[4]; const short* bSH[2]; const short* bSL[2];
    int aLo[4], bLo[2];
#pragma unroll
    for (int j = 0; j < 4; ++j) {
        int o = j * 4096 + tid * 16;
        int c = swz(o); int r = c >> 7, col = (c & 127) >> 1;
        aSH[j] = pAh + (long)(m0 + r) * lda + col;
        aLo[j] = o >> 1;
    }
#pragma unroll
    for (int j = 0; j < 2; ++j) {
        int o = j * 4096 + tid * 16;
        int c = swz(o); int r = c >> 7, col = (c & 127) >> 1;
        bSH[j] = pBh + (long)(n0 + r) * ldb + col;
        if (TERMS == 2) bSL[j] = pBl + (long)(n0 + r) * ldb + col;
        bLo[j] = o >> 1;
    }

    int oa[4][2], ob[2][2];
#pragma unroll
    for (int mf = 0; mf < 4; ++mf)
#pragma unroll
        for (int kf = 0; kf < 2; ++kf) {
            int row = wr * 64 + mf * 16 + (lane & 15);
            oa[mf][kf] = swz(row * 128 + (kf * 32 + ((lane >> 4) << 3)) * 2) >> 1;
        }
#pragma unroll
    for (int nf = 0; nf < 2; ++nf)
#pragma unroll
        for (int kf = 0; kf < 2; ++kf) {
            int row = wc * 32 + nf * 16 + (lane & 15);
            ob[nf][kf] = swz(row * 128 + (kf * 32 + ((lane >> 4) << 3)) * 2) >> 1;
        }

    f32x4 acc[4][2] = {};
    int Klim = KCAUSAL ? (K < m0 + 128 ? K : m0 + 128) : K;

    for (int k0 = 0; k0 < Klim; k0 += 64) {
#pragma unroll
        for (int j = 0; j < 4; ++j) {
            GLOAD16(aSH[j], LAh + aLo[j]);
            aSH[j] += 64;
        }
        long bstep = (BJUMP && k0 == 192) ? (1048576L - 192L) : 64L;
#pragma unroll
        for (int j = 0; j < 2; ++j) {
            GLOAD16(bSH[j], LBh + bLo[j]);
            bSH[j] += bstep;
            if (TERMS == 2) { GLOAD16(bSL[j], LBl + bLo[j]); bSL[j] += bstep; }
        }
        __syncthreads();
#pragma unroll
        for (int kf = 0; kf < 2; ++kf) {
            f16x8 vbh[2], vbl[2];
#pragma unroll
            for (int nf = 0; nf < 2; ++nf) {
                vbh[nf] = *(const f16x8*)(LBh + ob[nf][kf]);
                if (TERMS == 2) vbl[nf] = *(const f16x8*)(LBl + ob[nf][kf]);
            }
#pragma unroll
            for (int mf = 0; mf < 4; ++mf) {
                f16x8 vah = *(const f16x8*)(LAh + oa[mf][kf]);
#pragma unroll
                for (int nf = 0; nf < 2; ++nf) {
                    acc[mf][nf] = MFMAH(vah, vbh[nf], acc[mf][nf]);
                    if (TERMS == 2) acc[mf][nf] = MFMAH(vah, vbl[nf], acc[mf][nf]);
                }
            }
        }
        __syncthreads();
    }

#pragma unroll
    for (int mf = 0; mf < 4; ++mf)
#pragma unroll
        for (int nf = 0; nf < 2; ++nf) {
            f32x4 v = acc[mf][nf];
            int col  = n0 + wc * 32 + nf * 16 + (lane & 15);
            int rowb = m0 + wr * 64 + mf * 16 + ((lane >> 4) << 2);
            if (BMODE == 1) {
#pragma unroll
                for (int r = 0; r < 4; ++r) {
                    int t = (rowb + r) & 255;
                    v[r] += biasF[zLo * hsBias + (long)(64 + t) * ldbias + col];
                }
            } else if (BMODE == 3) {
#pragma unroll
                for (int r = 0; r < 4; ++r) {
                    int t = (rowb + r) & 255;
                    v[r] += biasF[(long)(col - n0) * 2880 + (n0 >> 6) * 960 + 64 + t];
                }
            }
            if (OUTU) {
                if (n0 == 0) {
#pragma unroll
                    for (int r = 0; r < 4; ++r)
                        Cf[(long)(rowb + r) * ldcf + col] = v[r];
                } else {
                    int head = (n0 >> 6) - 1;
                    int o = col - n0;
                    short hs[4];
#pragma unroll
                    for (int r = 0; r < 4; ++r) hs[r] = f2h(v[r]);
                    short4v th = {hs[0], hs[1], hs[2], hs[3]};
                    *(short4v*)(UThi + head * 1048576L + (long)o * 16384 + rowb) = th;
                }
            } else if (ACC) {
#pragma unroll
                for (int r = 0; r < 4; ++r)
                    Cf[zLo * sCf + (long)(rowb + r) * ldcf + col] += v[r];
            } else if (Cf) {
#pragma unroll
                for (int r = 0; r < 4; ++r)
                    Cf[zLo * sCf + (long)(rowb + r) * ldcf + col] = v[r];
            } else {
#pragma unroll
                for (int r = 0; r < 4; ++r) {
                    float f = v[r];
                    short hi = f2h(f);
                    Chi[zHi * hsC + zLo * sCh + (long)(rowb + r) * ldch + col] = hi;
                    if (Clo)
                        Clo[zHi * hsC + zLo * sCh + (long)(rowb + r) * ldch + col] = f2h(f - h2f(hi));
                }
            }
        }
}

// ================= helpers =================
__global__ __launch_bounds__(256) void build_h_rows(const float* __restrict__ x,
                                                    short* __restrict__ hhi) {
    int idx = blockIdx.x * 256 + threadIdx.x;
    int bt = idx >> 6, c = idx & 63;
    hhi[(long)bt * DC + c] = f2h(x[(long)bt * NS + c]);
}

__global__ __launch_bounds__(256) void build_hT_x(const float* __restrict__ x,
                                                  short* __restrict__ hTh) {
    __shared__ float tile[32][33];
    int c0 = blockIdx.x * 32, t0 = blockIdx.y * 32, b = blockIdx.z;
    int tx = threadIdx.x, ty = threadIdx.y;
    const float* xb = x + (long)b * NT * NS;
#pragma unroll
    for (int i = ty; i < 32; i += 8) tile[i][tx] = xb[(long)(t0 + i) * NS + c0 + tx];
    __syncthreads();
    long base = (long)b * (NS * 256);
#pragma unroll
    for (int i = ty; i < 32; i += 8)
        hTh[base + (long)(c0 + i) * 256 + t0 + tx] = f2h(tile[tx][i]);
}

__global__ void build_At(const float* __restrict__ A,
                         short* __restrict__ hi,
                         int dN, int dK, int srcLd, int shift, int dSrcN) {
    __shared__ float tile[32][33];
    int k0 = blockIdx.x * 32, n0 = blockIdx.y * 32;
    long hbase = (long)blockIdx.z * srcLd * srcLd;
    int tx = threadIdx.x, ty = threadIdx.y;
#pragma unroll
    for (int i = ty; i < 32; i += 8) {
        int k = k0 + i;
        int srck = (k < 64) ? k : k + shift;
        tile[i][tx] = (n0 + tx < dSrcN) ? A[hbase + (long)srck * srcLd + n0 + tx] : 0.f;
    }
    __syncthreads();
    long obase = (long)blockIdx.z * dN * dK;
#pragma unroll
    for (int i = ty; i < 32; i += 8)
        hi[obase + (long)(n0 + i) * dK + k0 + tx] = f2h(tile[tx][i]);
}

__global__ __launch_bounds__(256) void build_Wf(const float* __restrict__ Wo,
                                                short* __restrict__ hi) {
    int idx = blockIdx.x * 256 + threadIdx.x;
    if (idx >= 192 * DC) return;
    int r = idx / DC, kc = idx - r * DC;
    int o = r & 63, chunk = r >> 6;
    int srck = (kc < 64) ? kc : kc + 256;
    hi[idx] = f2h(Wo[(long)o * ND2 + chunk * 960 + srck]);
}

// causal softmax: merged heads (row>>14 = head), writes P fp16
__global__ __launch_bounds__(256) void softmax_split(const float* S,
                                                     short* pHi,
                                                     int ldo, long hs) {
    int row  = blockIdx.x * 4 + (threadIdx.x >> 6);
    int t    = row & (NT - 1);
    int hrow = row & 16383;
    int head = row >> 14;
    int lane = threadIdx.x & 63;
    int s0   = lane << 2;
    const float* p = S + (long)row * NT;

    float4 v = *(const float4*)(p + s0);
    float vv[4] = {v.x, v.y, v.z, v.w};
    float mx = -INFINITY;
#pragma unroll
    for (int j = 0; j < 4; ++j)
        if (s0 + j <= t) mx = fmaxf(mx, vv[j]);
    for (int off = 32; off; off >>= 1) mx = fmaxf(mx, __shfl_down(mx, off));
    mx = __shfl(mx, 0);

    float e[4]; float sum = 0.f;
#pragma unroll
    for (int j = 0; j < 4; ++j) {
        e[j] = (s0 + j <= t) ? __expf(vv[j] - mx) : 0.f;
        sum += e[j];
    }
    for (int off = 32; off; off >>= 1) sum += __shfl_down(sum, off);
    sum = __shfl(sum, 0);
    float inv = 1.f / sum;

    short hsv[4];
#pragma unroll
    for (int j = 0; j < 4; ++j) hsv[j] = f2h(e[j] * inv);
    short4v hv = {hsv[0], hsv[1], hsv[2], hsv[3]};
    *(short4v*)(pHi + (long)head * hs + (long)hrow * ldo + s0) = hv;
}

// ================= fp32 fallback (round-1, known-good) =================
__global__ __launch_bounds__(256) void build_h0(const float* __restrict__ x,
                                                float* __restrict__ h) {
    int idx = blockIdx.x * 256 + threadIdx.x;
    int bt = idx / ND0;
    int c  = idx - bt * ND0;
    int t  = bt & (NT - 1);
    float v;
    if (c < NS) v = x[(long)bt * NS + c];
    else        v = ((c - NS) == t) ? 1.0f : 0.0f;
    h[(long)bt * ND2 + c] = v;
}

template <bool BT, bool CAUSAL>
__global__ __launch_bounds__(256) void gemm64(
    const float* __restrict__ A, int lda, long sA,
    const float* __restrict__ Bm, int ldb, long sB,
    float* __restrict__ C, int ldc, long sC, int K)
{
    int m0 = blockIdx.y * 64, n0 = blockIdx.x * 64;
    if (CAUSAL && n0 > m0 + 63) return;
    long z = blockIdx.z;
    A += z * sA; Bm += z * sB; C += z * sC;

    __shared__ float As[16][68];
    __shared__ float Bs[16][68];

    int tid = threadIdx.x;
    int tx = tid & 15, ty = tid >> 4;
    int rowA = tid >> 2, kA = (tid & 3) << 2;
    int kB = tid >> 4,  colB = (tid & 15) << 2;

    float acc[4][4] = {};

    for (int k0 = 0; k0 < K; k0 += 16) {
        float4 av = *(const float4*)(A + (long)(m0 + rowA) * lda + k0 + kA);
        As[kA + 0][rowA] = av.x; As[kA + 1][rowA] = av.y;
        As[kA + 2][rowA] = av.z; As[kA + 3][rowA] = av.w;
        if (BT) {
            float4 bv = *(const float4*)(Bm + (long)(n0 + rowA) * ldb + k0 + kA);
            Bs[kA + 0][rowA] = bv.x; Bs[kA + 1][rowA] = bv.y;
            Bs[kA + 2][rowA] = bv.z; Bs[kA + 3][rowA] = bv.w;
        } else {
            float4 bv = *(const float4*)(Bm + (long)(k0 + kB) * ldb + n0 + colB);
            *(float4*)(&Bs[kB][colB]) = bv;
        }
        __syncthreads();
#pragma unroll
        for (int kk = 0; kk < 16; ++kk) {
            float4 a4 = *(const float4*)(&As[kk][ty << 2]);
            float4 b4 = *(const float4*)(&Bs[kk][tx << 2]);
            float a[4] = {a4.x, a4.y, a4.z, a4.w};
            float b[4] = {b4.x, b4.y, b4.z, b4.w};
#pragma unroll
            for (int i = 0; i < 4; ++i)
#pragma unroll
                for (int j = 0; j < 4; ++j)
                    acc[i][j] += a[i] * b[j];
        }
        __syncthreads();
    }
#pragma unroll
    for (int i = 0; i < 4; ++i) {
        float4 v = {acc[i][0], acc[i][1], acc[i][2], acc[i][3]};
        *(float4*)(C + (long)(m0 + (ty << 2) + i) * ldc + n0 + (tx << 2)) = v;
    }
}

__global__ __launch_bounds__(256) void softmax_causal(float* __restrict__ P) {
    int row  = blockIdx.x * 4 + (threadIdx.x >> 6);
    int t    = row & (NT - 1);
    int lane = threadIdx.x & 63;
    int s0   = lane << 2;
    float* p = P + (long)row * NT;

    float4 v = *(const float4*)(p + s0);
    float vv[4] = {v.x, v.y, v.z, v.w};
    float mx = -INFINITY;
#pragma unroll
    for (int j = 0; j < 4; ++j)
        if (s0 + j <= t) mx = fmaxf(mx, vv[j]);
    for (int off = 32; off; off >>= 1) mx = fmaxf(mx, __shfl_down(mx, off));
    mx = __shfl(mx, 0);

    float e[4]; float sum = 0.f;
#pragma unroll
    for (int j = 0; j < 4; ++j) {
        e[j] = (s0 + j <= t) ? __expf(vv[j] - mx) : 0.f;
        sum += e[j];
    }
    for (int off = 32; off; off >>= 1) sum += __shfl_down(sum, off);
    sum = __shfl(sum, 0);
    float inv = 1.f / sum;
    float4 o = {e[0] * inv, e[1] * inv, e[2] * inv, e[3] * inv};
    *(float4*)(p + s0) = o;
}

// ================= launch =================
extern "C" void kernel_launch(void* const* d_in, const int* in_sizes, int n_in,
                              void* d_out, int out_size, void* d_ws, size_t ws_size,
                              hipStream_t stream) {
    const float* x  = (const float*)d_in[0];
    const float* A0 = (const float*)d_in[1];
    const float* A1 = (const float*)d_in[2];
    const float* Wo = (const float*)d_in[3];
    float* out = (float*)d_out;

    if (ws_size >= 175120384UL) {
        char* wsb = (char*)d_ws;
        short* hc_hi = (short*)(wsb);                    // [16384][704]
        short* G_hi  = (short*)(wsb + 46137344L);        // [16384][1920] (<= 67MB slot)
        float* S     = (float*)(wsb + 113246208L);       // [128][256][256]
        short* P     = (short*)(wsb + 146800640L);       // [16384][512] both-head P
        short* hT_hi = (short*)(wsb + 163577856L);       // [64][64][256]
        short* At_hi = (short*)(wsb + 167772160L);       // [1920][704] (A1) / [2][320][64] (A0)
        short* Wf_hi = (short*)(wsb + 170655744L);       // [192][704]
        short* UT_hi = (short*)(wsb + 170926080L);       // [2][64][16384], end 175120384

        build_h_rows<<<4096, 256, 0, stream>>>(x, hc_hi);
        build_hT_x<<<dim3(2, 8, 64), dim3(32, 8), 0, stream>>>(x, hT_hi);
        build_Wf<<<528, 256, 0, stream>>>(Wo, Wf_hi);

        // -------- layer 0 (K=64 after pos-fold) --------
        build_At<<<dim3(2, 10, 2), dim3(32, 8), 0, stream>>>(A0, At_hi, ND0, 64, ND0, 0, ND0);
        // G0 = x @ A0^T + A0[64+t,:] -> G_hi [16384][640], both heads (z=2: zLo=head)
        gemm_mfma<1, 1, false, false, false, false><<<dim3(5, 128, 2), 256, 0, stream>>>(
            hc_hi, DC, 0L,
            At_hi, nullptr, 64, 20480L, 0L,
            nullptr, 0, 0L, G_hi, nullptr, 640, 320L,
            A0, 320L, 102400L,
            0L, 0L,
            nullptr, 64);
        // S = G0_x @ x^T + G0[.,64+s]  causal, both heads (z=128), 1-term B
        gemm128<0, 1, false><<<dim3(2, 2, 128), 256, 0, stream>>>(
            G_hi, 640, 163840L,
            hc_hi, nullptr, DC, 180224L,
            S, NT, 65536L,
            G_hi, 640L,
            320L, 4194304L, 64);
        softmax_split<<<8192, 256, 0, stream>>>(S, hc_hi + 128, DC, 320L);
        // PV0: hc[., 64+head*320 ..] = P @ x  (both heads, z=128), 1-term B
        gemm_mfma<0, 1, true, false, false, false><<<dim3(1, 2, 128), 256, 0, stream>>>(
            hc_hi + 128, DC, 180224L,
            hT_hi, nullptr, 256, 16384L, 0L,
            nullptr, 0, 0L,
            hc_hi + 64, nullptr, DC, 180224L,
            nullptr, 0L, 0L,
            320L, 320L,
            nullptr, 256);

        // -------- fused out-base + U heads (N=192, 1-term, U hi-only) --------
        gemm_mfma<3, 1, false, false, true, false><<<dim3(3, 128, 1), 256, 0, stream>>>(
            hc_hi, DC, 0L,
            Wf_hi, nullptr, DC, 0L, 0L,
            out, NS, 0L, nullptr, nullptr, 0, 0L,
            Wo, 0L, 0L,
            0L, 0L,
            UT_hi, DC);

        // -------- layer 1 --------
        // At as single [1920][704] (heads contiguous, no pad)
        build_At<<<dim3(22, 30, 2), dim3(32, 8), 0, stream>>>(A1, At_hi, 960, DC, ND1, 256, ND1);
        // G1 = hc @ At^T + pos bias: 256x128 tile, N=1920, XCD swizzle (960 wgs)
        gemmG1<<<960, 256, 0, stream>>>(hc_hi, At_hi, G_hi, A1);
        // S = G1[compact] @ hc^T + G1[.,64+s]  causal, AJUMP, both heads (z=128)
        gemm128<0, 1, true><<<dim3(2, 2, 128), 256, 0, stream>>>(
            G_hi, 1920, 491520L,
            hc_hi, nullptr, DC, 180224L,
            S, NT, 65536L,
            G_hi, 1920L,
            960L, 4194304L, DC);
        // P packed both heads per row: [16384][512], head offset 256
        softmax_split<<<8192, 256, 0, stream>>>(S, P, 512, 256L);
        // out += [P0|P1] @ [U0;U1]^T  (single dispatch, K=512, BJUMP at k=192->head1)
        gemm_mfma<0, 1, false, true, false, true><<<dim3(1, 2, 64), 256, 0, stream>>>(
            P, 512, 131072L,
            UT_hi, nullptr, 16384, 256L, 0L,
            out, NS, 16384L, nullptr, nullptr, 0, 0L,
            nullptr, 0L, 0L,
            0L, 0L,
            nullptr, 512);
        return;
    }

    // ---------- fp32 fallback ----------
    float* ws = (float*)d_ws;
    float* h  = ws;
    float* G  = ws + 47185920L;
    float* Pf = ws + 47185920L + 15728640L;

    build_h0<<<(NB * NT * ND0) / 256, 256, 0, stream>>>(x, h);

    for (int layer = 0; layer < 2; ++layer) {
        int d = layer ? ND1 : ND0;
        const float* Am = layer ? A1 : A0;
        for (int head = 0; head < NH; ++head) {
            const float* Ah = Am + (long)head * d * d;
            gemm64<false, false><<<dim3(d / 64, 256, 1), 256, 0, stream>>>(
                h, ND2, 0L, Ah, d, 0L, G, d, 0L, d);
            gemm64<true, true><<<dim3(4, 4, NB), 256, 0, stream>>>(
                G, d, (long)NT * d, h, ND2, (long)NT * ND2,
                Pf, NT, (long)NT * NT, d);
            softmax_causal<<<(NB * NT) / 4, 256, 0, stream>>>(Pf);
            gemm64<false, false><<<dim3(d / 64, 4, NB), 256, 0, stream>>>(
                Pf, NT, (long)NT * NT, h, ND2, (long)NT * ND2,
                h + (long)d * (1 + head), ND2, (long)NT * ND2, NT);
        }
    }
    gemm64<true, false><<<dim3(1, 256, 1), 256, 0, stream>>>(
        h, ND2, 0L, Wo, ND2, 0L, out, NS, 0L, ND2);
}

// Round 16
// 172.323 us; speedup vs baseline: 1.3147x; 1.0303x over previous
//
#include <hip/hip_runtime.h>
#include <math.h>

#define NB 64
#define NT 256
#define NS 64
#define ND0 320
#define ND1 960
#define ND2 2880
#define NH 2
#define DC 704    // compact h width: [x(64) | A00x(64) | P00(256) | A01x(64) | P01(256)]

typedef __attribute__((ext_vector_type(8))) _Float16 f16x8;
typedef __attribute__((ext_vector_type(4))) float f32x4;
typedef __attribute__((ext_vector_type(4))) short short4v;

typedef const __attribute__((address_space(1))) void* gas_ptr;
typedef __attribute__((address_space(3))) void* las_ptr;
#define GLOAD16(g, l) __builtin_amdgcn_global_load_lds((gas_ptr)(g), (las_ptr)(l), 16, 0, 0)
#define MFMAH(a, b, c) __builtin_amdgcn_mfma_f32_16x16x32_f16((a), (b), (c), 0, 0, 0)

__device__ __forceinline__ short f2h(float v) {
    union { _Float16 h; short s; } u; u.h = (_Float16)v; return u.s;
}
__device__ __forceinline__ float h2f(short b) {
    union { _Float16 h; short s; } u; u.s = b; return (float)u.h;
}
__device__ __forceinline__ int swz(int o) { return o ^ (((o >> 7) & 7) << 4); }    // 128B rows

// ================= G1: 256x128 fp16 GEMM, BK=32 double-buffered =================
// G[m,col] = sum_k hc[m,k]*At[col,k] + A1 pos bias. N=1920, 22 K-tiles of 32.
// 2-phase pipeline (T3-minimum): STAGE(t+1)->buf^1 issued BEFORE compute(t);
// ONE __syncthreads per tile (implicit vmcnt(0) drains prefetch at rendezvous).
// Race ledger: reads of buf^1 (iter t-1) retired before barrier(t-1) < STAGE
// issue (iter t); STAGE(t+1) landed at barrier(t) < reads (iter t+1).
// Sub-rows: 2 x 32-short rows packed per 128B line; swz keeps b128 reads 2-way.
__global__ __launch_bounds__(256, 2) void gemmG1(
    const short* __restrict__ hc,
    const short* __restrict__ At,
    short* __restrict__ G,
    const float* __restrict__ A1)
{
    int wg = blockIdx.x;
    int q8 = gridDim.x >> 3;           // 120
    int sid = (wg & 7) * q8 + (wg >> 3);
    int bx = sid % 15, by = sid / 15;
    int m0 = by << 8, n0 = bx << 7;

    __shared__ short lds[24576];       // buf0: A@0(8192) B@8192(4096); buf1: A@12288 B@20480
    int tid = threadIdx.x;
    int lane = tid & 63, w = tid >> 6;
    int wm = w >> 1, wn = w & 1;       // 2x2 waves, wave tile 128x64
    int q = lane >> 4, l15 = lane & 15;

    // staging: dest linear, source swz-decoded (row = sr*2 + half, k within 32)
    const short* aS[4]; const short* bS[2];
    int dA[4], dB[2];
#pragma unroll
    for (int j = 0; j < 4; ++j) {
        int o = j * 4096 + tid * 16;
        int c = swz(o);
        int sr = c >> 7, byt = c & 127;
        int row = sr * 2 + (byt >> 6), k = (byt & 63) >> 1;
        aS[j] = hc + (long)(m0 + row) * DC + k;
        dA[j] = o >> 1;
    }
#pragma unroll
    for (int j = 0; j < 2; ++j) {
        int o = j * 4096 + tid * 16;
        int c = swz(o);
        int sr = c >> 7, byt = c & 127;
        int row = sr * 2 + (byt >> 6), k = (byt & 63) >> 1;
        bS[j] = At + (long)(n0 + row) * DC + k;
        dB[j] = o >> 1;
    }

#define STG(BUF) { \
    GLOAD16(aS[0], lds + (BUF) + dA[0]); GLOAD16(aS[1], lds + (BUF) + dA[1]); \
    GLOAD16(aS[2], lds + (BUF) + dA[2]); GLOAD16(aS[3], lds + (BUF) + dA[3]); \
    GLOAD16(bS[0], lds + (BUF) + 8192 + dB[0]); GLOAD16(bS[1], lds + (BUF) + 8192 + dB[1]); \
    aS[0] += 32; aS[1] += 32; aS[2] += 32; aS[3] += 32; bS[0] += 32; bS[1] += 32; }

    // per-lane LDS read offsets (shorts, region-relative)
    int oa[8], ob[4];
#pragma unroll
    for (int mf = 0; mf < 8; ++mf) {
        int row = wm * 128 + mf * 16 + l15;
        int sr = row >> 1, half = row & 1;
        oa[mf] = swz(sr * 128 + half * 64 + q * 16) >> 1;
    }
#pragma unroll
    for (int nf = 0; nf < 4; ++nf) {
        int row = wn * 64 + nf * 16 + l15;
        int sr = row >> 1, half = row & 1;
        ob[nf] = swz(sr * 128 + half * 64 + q * 16) >> 1;
    }

    f32x4 acc[8][4] = {};

    STG(0)                              // tile 0 -> buf0
    __syncthreads();
#pragma unroll 2
    for (int t = 0; t < 22; ++t) {
        int cur = (t & 1) * 12288;
        if (t < 21) STG(12288 - cur)    // tile t+1 -> buf^1 (in flight over MFMA)
        f16x8 vb[4];
#pragma unroll
        for (int nf = 0; nf < 4; ++nf)
            vb[nf] = *(const f16x8*)(lds + cur + 8192 + ob[nf]);
#pragma unroll
        for (int mf = 0; mf < 8; ++mf) {
            f16x8 va = *(const f16x8*)(lds + cur + oa[mf]);
#pragma unroll
            for (int nf = 0; nf < 4; ++nf)
                acc[mf][nf] = MFMAH(va, vb[nf], acc[mf][nf]);
        }
        __syncthreads();                // vmcnt(0)+lgkm drain + barrier: tile t+1 ready
    }
#undef STG

    // epilogue: pos-bias fold + fp16 write
#pragma unroll
    for (int mf = 0; mf < 8; ++mf)
#pragma unroll
        for (int nf = 0; nf < 4; ++nf) {
            int col = n0 + wn * 64 + nf * 16 + l15;
            int head = (col >= 960) ? 1 : 0;
            int colh = col - head * 960;
            const float* bA = A1 + (long)head * 921600 + colh;
            int rowb = m0 + wm * 128 + mf * 16 + (q << 2);
#pragma unroll
            for (int r = 0; r < 4; ++r) {
                int t = (rowb + r) & 255;
                float f = acc[mf][nf][r] + bA[(long)(64 + t) * 960];
                G[(long)(rowb + r) * 1920 + col] = f2h(f);
            }
        }
}

// ================= 128x128 fp16 MFMA GEMM (scores, fp16 S out) =================
// S[m,n] = sum_k A[m,k]*B[n,k] + gather bias; causal tile skip; fp16 S write.
// AJUMP: A cols jump +256 after first K-step.
template <bool AJUMP>
__global__ __launch_bounds__(256, 3) void gemm128(
    const short* Ah, int lda, long sA,
    const short* Bh, int ldb, long sB,
    short* Sf, int ldcf, long sCf,
    const short* biasH, long ldbias,
    long hsA, long hsC,
    int K)
{
    int bx = blockIdx.x, by = blockIdx.y;
    int m0 = by * 128, n0 = bx * 128;
    if (n0 > m0 + 127) return;   // causal tile skip
    long zLo = blockIdx.z & 63, zHi = blockIdx.z >> 6;
    const short* pAh = Ah + zLo * sA + zHi * hsA;
    const short* pBh = Bh + zLo * sB;

    __shared__ short lds[16384];  // A 8192 | B 8192
    short* LAh = lds;
    short* LBh = lds + 8192;

    int tid = threadIdx.x;
    int lane = tid & 63, w = tid >> 6;
    int wr = w >> 1, wc = w & 1;

    const short* aSH[4]; const short* bSH[4];
    int aLo[4], bLo[4];
#pragma unroll
    for (int j = 0; j < 4; ++j) {
        int o = j * 4096 + tid * 16;
        int c = swz(o); int r = c >> 7, col = (c & 127) >> 1;
        aSH[j] = pAh + (long)(m0 + r) * lda + col;
        aLo[j] = o >> 1;
        bSH[j] = pBh + (long)(n0 + r) * ldb + col;
        bLo[j] = o >> 1;
    }

    int oa[4][2], ob[4][2];
#pragma unroll
    for (int mf = 0; mf < 4; ++mf)
#pragma unroll
        for (int kf = 0; kf < 2; ++kf) {
            int row = wr * 64 + mf * 16 + (lane & 15);
            oa[mf][kf] = swz(row * 128 + (kf * 32 + ((lane >> 4) << 3)) * 2) >> 1;
        }
#pragma unroll
    for (int nf = 0; nf < 4; ++nf)
#pragma unroll
        for (int kf = 0; kf < 2; ++kf) {
            int row = wc * 64 + nf * 16 + (lane & 15);
            ob[nf][kf] = swz(row * 128 + (kf * 32 + ((lane >> 4) << 3)) * 2) >> 1;
        }

    f32x4 acc[4][4] = {};

    for (int k0 = 0; k0 < K; k0 += 64) {
        int step = (AJUMP && k0 == 0) ? 320 : 64;
#pragma unroll
        for (int j = 0; j < 4; ++j) {
            GLOAD16(aSH[j], LAh + aLo[j]);
            aSH[j] += step;
            GLOAD16(bSH[j], LBh + bLo[j]);
            bSH[j] += 64;
        }
        __syncthreads();
#pragma unroll
        for (int kf = 0; kf < 2; ++kf) {
            f16x8 vbh[4];
#pragma unroll
            for (int nf = 0; nf < 4; ++nf)
                vbh[nf] = *(const f16x8*)(LBh + ob[nf][kf]);
#pragma unroll
            for (int mf = 0; mf < 4; ++mf) {
                f16x8 vah = *(const f16x8*)(LAh + oa[mf][kf]);
#pragma unroll
                for (int nf = 0; nf < 4; ++nf)
                    acc[mf][nf] = MFMAH(vah, vbh[nf], acc[mf][nf]);
            }
        }
        __syncthreads();
    }

#pragma unroll
    for (int mf = 0; mf < 4; ++mf)
#pragma unroll
        for (int nf = 0; nf < 4; ++nf) {
            f32x4 v = acc[mf][nf];
            int col  = n0 + wc * 64 + nf * 16 + (lane & 15);
            int rowb = m0 + wr * 64 + mf * 16 + ((lane >> 4) << 2);
#pragma unroll
            for (int r = 0; r < 4; ++r) {
                long o = (zLo * 256 + rowb + r) * ldbias + 64 + col + zHi * hsA;
                v[r] += h2f(biasH[o]);
            }
#pragma unroll
            for (int r = 0; r < 4; ++r)
                Sf[zLo * sCf + zHi * hsC + (long)(rowb + r) * ldcf + col] = f2h(v[r]);
        }
}

// ================= 128x64 fp16 MFMA GEMM (small-N ops) =================
// BMODE: 0 none; 1 bias=biasF[zLo*hsBias+(64+t)*ldbias+col]; 3 OutU Wo pos fold
// BJUMP: B pointer jumps to head1 (UT stride 1048576) after k-tile 192.
template <int BMODE, bool KCAUSAL, bool ACC, bool OUTU, bool BJUMP>
__global__ __launch_bounds__(256) void gemm_mfma(
    const short* Ah, int lda, long sA,
    const short* Bh, int ldb, long sB, long hsB,
    float* Cf, int ldcf, long sCf,
    short* Chi, int ldch, long sCh,
    const float* biasF, long ldbias, long hsBias,
    long hsA, long hsC,
    short* UThi,
    int K)
{
    int m0 = blockIdx.y * 128, n0 = blockIdx.x * 64;
    long zLo = blockIdx.z & 63, zHi = blockIdx.z >> 6;
    const short* pAh = Ah + zLo * sA + zHi * hsA;
    const short* pBh = Bh + zLo * sB + zHi * hsB;

    __shared__ short lds[12288]; // LAh 8192 | LBh 4096
    short* LAh = lds;
    short* LBh = lds + 8192;

    int tid = threadIdx.x;
    int lane = tid & 63, w = tid >> 6;
    int wr = w >> 1, wc = w & 1;

    const short* aSH[4]; const short* bSH[2];
    int aLo[4], bLo[2];
#pragma unroll
    for (int j = 0; j < 4; ++j) {
        int o = j * 4096 + tid * 16;
        int c = swz(o); int r = c >> 7, col = (c & 127) >> 1;
        aSH[j] = pAh + (long)(m0 + r) * lda + col;
        aLo[j] = o >> 1;
    }
#pragma unroll
    for (int j = 0; j < 2; ++j) {
        int o = j * 4096 + tid * 16;
        int c = swz(o); int r = c >> 7, col = (c & 127) >> 1;
        bSH[j] = pBh + (long)(n0 + r) * ldb + col;
        bLo[j] = o >> 1;
    }

    int oa[4][2], ob[2][2];
#pragma unroll
    for (int mf = 0; mf < 4; ++mf)
#pragma unroll
        for (int kf = 0; kf < 2; ++kf) {
            int row = wr * 64 + mf * 16 + (lane & 15);
            oa[mf][kf] = swz(row * 128 + (kf * 32 + ((lane >> 4) << 3)) * 2) >> 1;
        }
#pragma unroll
    for (int nf = 0; nf < 2; ++nf)
#pragma unroll
        for (int kf = 0; kf < 2; ++kf) {
            int row = wc * 32 + nf * 16 + (lane & 15);
            ob[nf][kf] = swz(row * 128 + (kf * 32 + ((lane >> 4) << 3)) * 2) >> 1;
        }

    f32x4 acc[4][2] = {};
    int Klim = KCAUSAL ? (K < m0 + 128 ? K : m0 + 128) : K;

    for (int k0 = 0; k0 < Klim; k0 += 64) {
#pragma unroll
        for (int j = 0; j < 4; ++j) {
            GLOAD16(aSH[j], LAh + aLo[j]);
            aSH[j] += 64;
        }
        long bstep = (BJUMP && k0 == 192) ? (1048576L - 192L) : 64L;
#pragma unroll
        for (int j = 0; j < 2; ++j) {
            GLOAD16(bSH[j], LBh + bLo[j]);
            bSH[j] += bstep;
        }
        __syncthreads();
#pragma unroll
        for (int kf = 0; kf < 2; ++kf) {
            f16x8 vbh[2];
#pragma unroll
            for (int nf = 0; nf < 2; ++nf)
                vbh[nf] = *(const f16x8*)(LBh + ob[nf][kf]);
#pragma unroll
            for (int mf = 0; mf < 4; ++mf) {
                f16x8 vah = *(const f16x8*)(LAh + oa[mf][kf]);
#pragma unroll
                for (int nf = 0; nf < 2; ++nf)
                    acc[mf][nf] = MFMAH(vah, vbh[nf], acc[mf][nf]);
            }
        }
        __syncthreads();
    }

#pragma unroll
    for (int mf = 0; mf < 4; ++mf)
#pragma unroll
        for (int nf = 0; nf < 2; ++nf) {
            f32x4 v = acc[mf][nf];
            int col  = n0 + wc * 32 + nf * 16 + (lane & 15);
            int rowb = m0 + wr * 64 + mf * 16 + ((lane >> 4) << 2);
            if (BMODE == 1) {
#pragma unroll
                for (int r = 0; r < 4; ++r) {
                    int t = (rowb + r) & 255;
                    v[r] += biasF[zLo * hsBias + (long)(64 + t) * ldbias + col];
                }
            } else if (BMODE == 3) {
#pragma unroll
                for (int r = 0; r < 4; ++r) {
                    int t = (rowb + r) & 255;
                    v[r] += biasF[(long)(col - n0) * 2880 + (n0 >> 6) * 960 + 64 + t];
                }
            }
            if (OUTU) {
                if (n0 == 0) {
#pragma unroll
                    for (int r = 0; r < 4; ++r)
                        Cf[(long)(rowb + r) * ldcf + col] = v[r];
                } else {
                    int head = (n0 >> 6) - 1;
                    int o = col - n0;
                    short hs[4];
#pragma unroll
                    for (int r = 0; r < 4; ++r) hs[r] = f2h(v[r]);
                    short4v th = {hs[0], hs[1], hs[2], hs[3]};
                    *(short4v*)(UThi + head * 1048576L + (long)o * 16384 + rowb) = th;
                }
            } else if (ACC) {
#pragma unroll
                for (int r = 0; r < 4; ++r)
                    Cf[zLo * sCf + (long)(rowb + r) * ldcf + col] += v[r];
            } else if (Cf) {
#pragma unroll
                for (int r = 0; r < 4; ++r)
                    Cf[zLo * sCf + (long)(rowb + r) * ldcf + col] = v[r];
            } else {
#pragma unroll
                for (int r = 0; r < 4; ++r)
                    Chi[zHi * hsC + zLo * sCh + (long)(rowb + r) * ldch + col] = f2h(v[r]);
            }
        }
}

// ================= merged prep builds =================
// blocks [0,4096): hc x-cols; [4096,5120): hT transpose; [5120,5648): Wf; [5648,5688): At0
__global__ __launch_bounds__(256) void build_all(const float* __restrict__ x,
                                                 const float* __restrict__ Wo,
                                                 const float* __restrict__ A0,
                                                 short* __restrict__ hc,
                                                 short* __restrict__ hT,
                                                 short* __restrict__ Wf,
                                                 short* __restrict__ At0) {
    __shared__ float tile[32][33];
    int blk = blockIdx.x;
    int tid = threadIdx.x;
    if (blk < 4096) {
        int idx = blk * 256 + tid;
        int bt = idx >> 6, c = idx & 63;
        hc[(long)bt * DC + c] = f2h(x[(long)bt * NS + c]);
    } else if (blk < 5120) {
        int i = blk - 4096;
        int c0 = (i & 1) * 32, t0 = ((i >> 1) & 7) * 32, b = i >> 4;
        int tx = tid & 31, ty = tid >> 5;
        const float* xb = x + (long)b * NT * NS;
#pragma unroll
        for (int ii = ty; ii < 32; ii += 8) tile[ii][tx] = xb[(long)(t0 + ii) * NS + c0 + tx];
        __syncthreads();
        long base = (long)b * (NS * 256);
#pragma unroll
        for (int ii = ty; ii < 32; ii += 8)
            hT[base + (long)(c0 + ii) * 256 + t0 + tx] = f2h(tile[tx][ii]);
    } else if (blk < 5648) {
        int idx = (blk - 5120) * 256 + tid;
        if (idx < 192 * DC) {
            int r = idx / DC, kc = idx - r * DC;
            int o = r & 63, chunk = r >> 6;
            int srck = (kc < 64) ? kc : kc + 256;
            Wf[idx] = f2h(Wo[(long)o * ND2 + chunk * 960 + srck]);
        }
    } else {
        int i = blk - 5648;                   // 40 = 2 k0 x 10 n0 x 2 z
        int k0 = (i & 1) * 32;
        int n0 = ((i >> 1) % 10) * 32;
        int z  = i / 20;
        int tx = tid & 31, ty = tid >> 5;
        long hbase = (long)z * ND0 * ND0;
#pragma unroll
        for (int ii = ty; ii < 32; ii += 8)
            tile[ii][tx] = A0[hbase + (long)(k0 + ii) * ND0 + n0 + tx];
        __syncthreads();
        long obase = (long)z * ND0 * 64;
#pragma unroll
        for (int ii = ty; ii < 32; ii += 8)
            At0[obase + (long)(n0 + ii) * 64 + k0 + tx] = f2h(tile[tx][ii]);
    }
}

// A1^T compact-K [1920][704]
__global__ void build_At(const float* __restrict__ A,
                         short* __restrict__ hi,
                         int dN, int dK, int srcLd, int shift, int dSrcN) {
    __shared__ float tile[32][33];
    int k0 = blockIdx.x * 32, n0 = blockIdx.y * 32;
    long hbase = (long)blockIdx.z * srcLd * srcLd;
    int tx = threadIdx.x, ty = threadIdx.y;
#pragma unroll
    for (int i = ty; i < 32; i += 8) {
        int k = k0 + i;
        int srck = (k < 64) ? k : k + shift;
        tile[i][tx] = (n0 + tx < dSrcN) ? A[hbase + (long)srck * srcLd + n0 + tx] : 0.f;
    }
    __syncthreads();
    long obase = (long)blockIdx.z * dN * dK;
#pragma unroll
    for (int i = ty; i < 32; i += 8)
        hi[obase + (long)(n0 + i) * dK + k0 + tx] = f2h(tile[tx][i]);
}

// causal softmax: fp16 S in, merged heads (row>>14 = head), writes P fp16
__global__ __launch_bounds__(256) void softmax_split(const short* S,
                                                     short* pHi,
                                                     int ldo, long hs) {
    int row  = blockIdx.x * 4 + (threadIdx.x >> 6);
    int t    = row & (NT - 1);
    int hrow = row & 16383;
    int head = row >> 14;
    int lane = threadIdx.x & 63;
    int s0   = lane << 2;
    const short* p = S + (long)row * NT;

    short4v sv = *(const short4v*)(p + s0);
    float vv[4] = {h2f(sv[0]), h2f(sv[1]), h2f(sv[2]), h2f(sv[3])};
    float mx = -INFINITY;
#pragma unroll
    for (int j = 0; j < 4; ++j)
        if (s0 + j <= t) mx = fmaxf(mx, vv[j]);
    for (int off = 32; off; off >>= 1) mx = fmaxf(mx, __shfl_down(mx, off));
    mx = __shfl(mx, 0);

    float e[4]; float sum = 0.f;
#pragma unroll
    for (int j = 0; j < 4; ++j) {
        e[j] = (s0 + j <= t) ? __expf(vv[j] - mx) : 0.f;
        sum += e[j];
    }
    for (int off = 32; off; off >>= 1) sum += __shfl_down(sum, off);
    sum = __shfl(sum, 0);
    float inv = 1.f / sum;

    short hsv[4];
#pragma unroll
    for (int j = 0; j < 4; ++j) hsv[j] = f2h(e[j] * inv);
    short4v hv = {hsv[0], hsv[1], hsv[2], hsv[3]};
    *(short4v*)(pHi + (long)head * hs + (long)hrow * ldo + s0) = hv;
}

// ================= fp32 fallback (round-1, known-good) =================
__global__ __launch_bounds__(256) void build_h0(const float* __restrict__ x,
                                                float* __restrict__ h) {
    int idx = blockIdx.x * 256 + threadIdx.x;
    int bt = idx / ND0;
    int c  = idx - bt * ND0;
    int t  = bt & (NT - 1);
    float v;
    if (c < NS) v = x[(long)bt * NS + c];
    else        v = ((c - NS) == t) ? 1.0f : 0.0f;
    h[(long)bt * ND2 + c] = v;
}

template <bool BT, bool CAUSAL>
__global__ __launch_bounds__(256) void gemm64(
    const float* __restrict__ A, int lda, long sA,
    const float* __restrict__ Bm, int ldb, long sB,
    float* __restrict__ C, int ldc, long sC, int K)
{
    int m0 = blockIdx.y * 64, n0 = blockIdx.x * 64;
    if (CAUSAL && n0 > m0 + 63) return;
    long z = blockIdx.z;
    A += z * sA; Bm += z * sB; C += z * sC;

    __shared__ float As[16][68];
    __shared__ float Bs[16][68];

    int tid = threadIdx.x;
    int tx = tid & 15, ty = tid >> 4;
    int rowA = tid >> 2, kA = (tid & 3) << 2;
    int kB = tid >> 4,  colB = (tid & 15) << 2;

    float acc[4][4] = {};

    for (int k0 = 0; k0 < K; k0 += 16) {
        float4 av = *(const float4*)(A + (long)(m0 + rowA) * lda + k0 + kA);
        As[kA + 0][rowA] = av.x; As[kA + 1][rowA] = av.y;
        As[kA + 2][rowA] = av.z; As[kA + 3][rowA] = av.w;
        if (BT) {
            float4 bv = *(const float4*)(Bm + (long)(n0 + rowA) * ldb + k0 + kA);
            Bs[kA + 0][rowA] = bv.x; Bs[kA + 1][rowA] = bv.y;
            Bs[kA + 2][rowA] = bv.z; Bs[kA + 3][rowA] = bv.w;
        } else {
            float4 bv = *(const float4*)(Bm + (long)(k0 + kB) * ldb + n0 + colB);
            *(float4*)(&Bs[kB][colB]) = bv;
        }
        __syncthreads();
#pragma unroll
        for (int kk = 0; kk < 16; ++kk) {
            float4 a4 = *(const float4*)(&As[kk][ty << 2]);
            float4 b4 = *(const float4*)(&Bs[kk][tx << 2]);
            float a[4] = {a4.x, a4.y, a4.z, a4.w};
            float b[4] = {b4.x, b4.y, b4.z, b4.w};
#pragma unroll
            for (int i = 0; i < 4; ++i)
#pragma unroll
                for (int j = 0; j < 4; ++j)
                    acc[i][j] += a[i] * b[j];
        }
        __syncthreads();
    }
#pragma unroll
    for (int i = 0; i < 4; ++i) {
        float4 v = {acc[i][0], acc[i][1], acc[i][2], acc[i][3]};
        *(float4*)(C + (long)(m0 + (ty << 2) + i) * ldc + n0 + (tx << 2)) = v;
    }
}

__global__ __launch_bounds__(256) void softmax_causal(float* __restrict__ P) {
    int row  = blockIdx.x * 4 + (threadIdx.x >> 6);
    int t    = row & (NT - 1);
    int lane = threadIdx.x & 63;
    int s0   = lane << 2;
    float* p = P + (long)row * NT;

    float4 v = *(const float4*)(p + s0);
    float vv[4] = {v.x, v.y, v.z, v.w};
    float mx = -INFINITY;
#pragma unroll
    for (int j = 0; j < 4; ++j)
        if (s0 + j <= t) mx = fmaxf(mx, vv[j]);
    for (int off = 32; off; off >>= 1) mx = fmaxf(mx, __shfl_down(mx, off));
    mx = __shfl(mx, 0);

    float e[4]; float sum = 0.f;
#pragma unroll
    for (int j = 0; j < 4; ++j) {
        e[j] = (s0 + j <= t) ? __expf(vv[j] - mx) : 0.f;
        sum += e[j];
    }
    for (int off = 32; off; off >>= 1) sum += __shfl_down(sum, off);
    sum = __shfl(sum, 0);
    float inv = 1.f / sum;
    float4 o = {e[0] * inv, e[1] * inv, e[2] * inv, e[3] * inv};
    *(float4*)(p + s0) = o;
}

// ================= launch =================
extern "C" void kernel_launch(void* const* d_in, const int* in_sizes, int n_in,
                              void* d_out, int out_size, void* d_ws, size_t ws_size,
                              hipStream_t stream) {
    const float* x  = (const float*)d_in[0];
    const float* A0 = (const float*)d_in[1];
    const float* A1 = (const float*)d_in[2];
    const float* Wo = (const float*)d_in[3];
    float* out = (float*)d_out;

    if (ws_size >= 175120384UL) {
        char* wsb = (char*)d_ws;
        short* hc_hi = (short*)(wsb);                    // [16384][704]
        short* G_hi  = (short*)(wsb + 46137344L);        // [16384][1920]
        short* S     = (short*)(wsb + 113246208L);       // [2][64][256][256] fp16
        short* P     = (short*)(wsb + 146800640L);       // [16384][512] both-head P
        short* hT_hi = (short*)(wsb + 163577856L);       // [64][64][256]
        short* At_hi = (short*)(wsb + 167772160L);       // [1920][704] (A1) / [2][320][64] (A0)
        short* Wf_hi = (short*)(wsb + 170655744L);       // [192][704]
        short* UT_hi = (short*)(wsb + 170926080L);       // [2][64][16384], end 175120384

        // merged prep: hc x-cols, hT, Wf, At0
        build_all<<<5688, 256, 0, stream>>>(x, Wo, A0, hc_hi, hT_hi, Wf_hi, At_hi);

        // -------- layer 0 (K=64 after pos-fold) --------
        // G0 = x @ A0^T + A0[64+t,:] -> G_hi [16384][640], both heads (z=2: zLo=head)
        gemm_mfma<1, false, false, false, false><<<dim3(5, 128, 2), 256, 0, stream>>>(
            hc_hi, DC, 0L,
            At_hi, 64, 20480L, 0L,
            nullptr, 0, 0L, G_hi, 640, 320L,
            A0, 320L, 102400L,
            0L, 0L,
            nullptr, 64);
        // S = G0_x @ x^T + G0[.,64+s]  causal, both heads (z=128), fp16 S
        gemm128<false><<<dim3(2, 2, 128), 256, 0, stream>>>(
            G_hi, 640, 163840L,
            hc_hi, DC, 180224L,
            S, NT, 65536L,
            G_hi, 640L,
            320L, 4194304L, 64);
        softmax_split<<<8192, 256, 0, stream>>>(S, hc_hi + 128, DC, 320L);
        // PV0: hc[., 64+head*320 ..] = P @ x  (both heads, z=128)
        gemm_mfma<0, true, false, false, false><<<dim3(1, 2, 128), 256, 0, stream>>>(
            hc_hi + 128, DC, 180224L,
            hT_hi, 256, 16384L, 0L,
            nullptr, 0, 0L,
            hc_hi + 64, DC, 180224L,
            nullptr, 0L, 0L,
            320L, 320L,
            nullptr, 256);

        // -------- fused out-base + U heads (N=192) --------
        gemm_mfma<3, false, false, true, false><<<dim3(3, 128, 1), 256, 0, stream>>>(
            hc_hi, DC, 0L,
            Wf_hi, DC, 0L, 0L,
            out, NS, 0L, nullptr, 0, 0L,
            Wo, 0L, 0L,
            0L, 0L,
            UT_hi, DC);

        // -------- layer 1 --------
        build_At<<<dim3(22, 30, 2), dim3(32, 8), 0, stream>>>(A1, At_hi, 960, DC, ND1, 256, ND1);
        // G1: 256x128 BK=32 dbuf, N=1920, XCD swizzle (960 wgs)
        gemmG1<<<960, 256, 0, stream>>>(hc_hi, At_hi, G_hi, A1);
        // S = G1[compact] @ hc^T + G1[.,64+s]  causal, AJUMP, both heads (z=128), fp16 S
        gemm128<true><<<dim3(2, 2, 128), 256, 0, stream>>>(
            G_hi, 1920, 491520L,
            hc_hi, DC, 180224L,
            S, NT, 65536L,
            G_hi, 1920L,
            960L, 4194304L, DC);
        // P packed both heads per row: [16384][512], head offset 256
        softmax_split<<<8192, 256, 0, stream>>>(S, P, 512, 256L);
        // out += [P0|P1] @ [U0;U1]^T  (single dispatch, K=512, BJUMP at k=192->head1)
        gemm_mfma<0, false, true, false, true><<<dim3(1, 2, 64), 256, 0, stream>>>(
            P, 512, 131072L,
            UT_hi, 16384, 256L, 0L,
            out, NS, 16384L, nullptr, 0, 0L,
            nullptr, 0L, 0L,
            0L, 0L,
            nullptr, 512);
        return;
    }

    // ---------- fp32 fallback ----------
    float* ws = (float*)d_ws;
    float* h  = ws;
    float* G  = ws + 47185920L;
    float* Pf = ws + 47185920L + 15728640L;

    build_h0<<<(NB * NT * ND0) / 256, 256, 0, stream>>>(x, h);

    for (int layer = 0; layer < 2; ++layer) {
        int d = layer ? ND1 : ND0;
        const float* Am = layer ? A1 : A0;
        for (int head = 0; head < NH; ++head) {
            const float* Ah = Am + (long)head * d * d;
            gemm64<false, false><<<dim3(d / 64, 256, 1), 256, 0, stream>>>(
                h, ND2, 0L, Ah, d, 0L, G, d, 0L, d);
            gemm64<true, true><<<dim3(4, 4, NB), 256, 0, stream>>>(
                G, d, (long)NT * d, h, ND2, (long)NT * ND2,
                Pf, NT, (long)NT * NT, d);
            softmax_causal<<<(NB * NT) / 4, 256, 0, stream>>>(Pf);
            gemm64<false, false><<<dim3(d / 64, 4, NB), 256, 0, stream>>>(
                Pf, NT, (long)NT * NT, h, ND2, (long)NT * ND2,
                h + (long)d * (1 + head), ND2, (long)NT * ND2, NT);
        }
    }
    gemm64<true, false><<<dim3(1, 256, 1), 256, 0, stream>>>(
        h, ND2, 0L, Wo, ND2, 0L, out, NS, 0L, ND2);
}

// Round 17
// 167.866 us; speedup vs baseline: 1.3496x; 1.0266x over previous
//
#include <hip/hip_runtime.h>
#include <math.h>

#define NB 64
#define NT 256
#define NS 64
#define ND0 320
#define ND1 960
#define ND2 2880
#define NH 2
#define DC 704    // compact h width: [x(64) | A00x(64) | P00(256) | A01x(64) | P01(256)]

typedef __attribute__((ext_vector_type(8))) _Float16 f16x8;
typedef __attribute__((ext_vector_type(4))) float f32x4;
typedef __attribute__((ext_vector_type(4))) short short4v;

typedef const __attribute__((address_space(1))) void* gas_ptr;
typedef __attribute__((address_space(3))) void* las_ptr;
#define GLOAD16(g, l) __builtin_amdgcn_global_load_lds((gas_ptr)(g), (las_ptr)(l), 16, 0, 0)
#define MFMAH(a, b, c) __builtin_amdgcn_mfma_f32_16x16x32_f16((a), (b), (c), 0, 0, 0)

__device__ __forceinline__ short f2h(float v) {
    union { _Float16 h; short s; } u; u.h = (_Float16)v; return u.s;
}
__device__ __forceinline__ float h2f(short b) {
    union { _Float16 h; short s; } u; u.s = b; return (float)u.h;
}
__device__ __forceinline__ int swz(int o) { return o ^ (((o >> 7) & 7) << 4); }    // 128B rows

// ================= G1 kernel: 256x128 fp16 GEMM, BK=64 (round-15 proven) =================
// G[m,col] = sum_k hc[m,k]*At[col,k] + A1 pos bias; N=1920, 11 K-tiles.
// 4 waves (2Mx2N), wave tile 128x64. LDS: A 32KB | B 16KB. XCD-bijective grid (960).
__global__ __launch_bounds__(256, 2) void gemmG1(
    const short* __restrict__ hc,
    const short* __restrict__ At,
    short* __restrict__ G,
    const float* __restrict__ A1)
{
    int wg = blockIdx.x;
    int q8 = gridDim.x >> 3;           // 120
    int sid = (wg & 7) * q8 + (wg >> 3);
    int bx = sid % 15, by = sid / 15;
    int m0 = by << 8, n0 = bx << 7;

    __shared__ short lds[24576];       // A 16384 shorts | B 8192 shorts
    int tid = threadIdx.x;
    int lane = tid & 63, w = tid >> 6;
    int wm = w >> 1, wn = w & 1;
    int q = lane >> 4, l15 = lane & 15;

    const short* aS[8]; const short* bS[4];
    int dA[8], dB[4];
#pragma unroll
    for (int j = 0; j < 8; ++j) {
        int o = j * 4096 + tid * 16;
        int c = swz(o); int r = c >> 7, col = (c & 127) >> 1;
        aS[j] = hc + (long)(m0 + r) * DC + col;
        dA[j] = o >> 1;
    }
#pragma unroll
    for (int j = 0; j < 4; ++j) {
        int o = j * 4096 + tid * 16;
        int c = swz(o); int r = c >> 7, col = (c & 127) >> 1;
        bS[j] = At + (long)(n0 + r) * DC + col;
        dB[j] = o >> 1;
    }

    int oa[8][2], ob[4][2];
#pragma unroll
    for (int mf = 0; mf < 8; ++mf)
#pragma unroll
        for (int kf = 0; kf < 2; ++kf) {
            int row = wm * 128 + mf * 16 + l15;
            oa[mf][kf] = swz(row * 128 + (kf * 32 + (q << 3)) * 2) >> 1;
        }
#pragma unroll
    for (int nf = 0; nf < 4; ++nf)
#pragma unroll
        for (int kf = 0; kf < 2; ++kf) {
            int row = wn * 64 + nf * 16 + l15;
            ob[nf][kf] = swz(row * 128 + (kf * 32 + (q << 3)) * 2) >> 1;
        }

    f32x4 acc[8][4] = {};

    for (int k0 = 0; k0 < DC; k0 += 64) {
#pragma unroll
        for (int j = 0; j < 8; ++j) { GLOAD16(aS[j], lds + dA[j]); aS[j] += 64; }
#pragma unroll
        for (int j = 0; j < 4; ++j) { GLOAD16(bS[j], lds + 16384 + dB[j]); bS[j] += 64; }
        __syncthreads();
#pragma unroll
        for (int kf = 0; kf < 2; ++kf) {
            f16x8 vb[4];
#pragma unroll
            for (int nf = 0; nf < 4; ++nf)
                vb[nf] = *(const f16x8*)(lds + 16384 + ob[nf][kf]);
#pragma unroll
            for (int mf = 0; mf < 8; ++mf) {
                f16x8 va = *(const f16x8*)(lds + oa[mf][kf]);
#pragma unroll
                for (int nf = 0; nf < 4; ++nf)
                    acc[mf][nf] = MFMAH(va, vb[nf], acc[mf][nf]);
            }
        }
        __syncthreads();
    }

#pragma unroll
    for (int mf = 0; mf < 8; ++mf)
#pragma unroll
        for (int nf = 0; nf < 4; ++nf) {
            int col = n0 + wn * 64 + nf * 16 + l15;
            int head = (col >= 960) ? 1 : 0;
            int colh = col - head * 960;
            const float* bA = A1 + (long)head * 921600 + colh;
            int rowb = m0 + wm * 128 + mf * 16 + (q << 2);
#pragma unroll
            for (int r = 0; r < 4; ++r) {
                int t = (rowb + r) & 255;
                float f = acc[mf][nf][r] + bA[(long)(64 + t) * 960];
                G[(long)(rowb + r) * 1920 + col] = f2h(f);
            }
        }
}

// ================= 128x128 fp16 MFMA GEMM (scores, fp16 S out) =================
// S[m,n] = sum_k A[m,k]*B[n,k] + gather bias; causal tile skip; fp16 S write.
// AJUMP: A cols jump +256 after first K-step.
template <bool AJUMP>
__global__ __launch_bounds__(256, 3) void gemm128(
    const short* Ah, int lda, long sA,
    const short* Bh, int ldb, long sB,
    short* Sf, int ldcf, long sCf,
    const short* biasH, long ldbias,
    long hsA, long hsC,
    int K)
{
    int bx = blockIdx.x, by = blockIdx.y;
    int m0 = by * 128, n0 = bx * 128;
    if (n0 > m0 + 127) return;   // causal tile skip
    long zLo = blockIdx.z & 63, zHi = blockIdx.z >> 6;
    const short* pAh = Ah + zLo * sA + zHi * hsA;
    const short* pBh = Bh + zLo * sB;

    __shared__ short lds[16384];  // A 8192 | B 8192
    short* LAh = lds;
    short* LBh = lds + 8192;

    int tid = threadIdx.x;
    int lane = tid & 63, w = tid >> 6;
    int wr = w >> 1, wc = w & 1;

    const short* aSH[4]; const short* bSH[4];
    int aLo[4], bLo[4];
#pragma unroll
    for (int j = 0; j < 4; ++j) {
        int o = j * 4096 + tid * 16;
        int c = swz(o); int r = c >> 7, col = (c & 127) >> 1;
        aSH[j] = pAh + (long)(m0 + r) * lda + col;
        aLo[j] = o >> 1;
        bSH[j] = pBh + (long)(n0 + r) * ldb + col;
        bLo[j] = o >> 1;
    }

    int oa[4][2], ob[4][2];
#pragma unroll
    for (int mf = 0; mf < 4; ++mf)
#pragma unroll
        for (int kf = 0; kf < 2; ++kf) {
            int row = wr * 64 + mf * 16 + (lane & 15);
            oa[mf][kf] = swz(row * 128 + (kf * 32 + ((lane >> 4) << 3)) * 2) >> 1;
        }
#pragma unroll
    for (int nf = 0; nf < 4; ++nf)
#pragma unroll
        for (int kf = 0; kf < 2; ++kf) {
            int row = wc * 64 + nf * 16 + (lane & 15);
            ob[nf][kf] = swz(row * 128 + (kf * 32 + ((lane >> 4) << 3)) * 2) >> 1;
        }

    f32x4 acc[4][4] = {};

    for (int k0 = 0; k0 < K; k0 += 64) {
        int step = (AJUMP && k0 == 0) ? 320 : 64;
#pragma unroll
        for (int j = 0; j < 4; ++j) {
            GLOAD16(aSH[j], LAh + aLo[j]);
            aSH[j] += step;
            GLOAD16(bSH[j], LBh + bLo[j]);
            bSH[j] += 64;
        }
        __syncthreads();
#pragma unroll
        for (int kf = 0; kf < 2; ++kf) {
            f16x8 vbh[4];
#pragma unroll
            for (int nf = 0; nf < 4; ++nf)
                vbh[nf] = *(const f16x8*)(LBh + ob[nf][kf]);
#pragma unroll
            for (int mf = 0; mf < 4; ++mf) {
                f16x8 vah = *(const f16x8*)(LAh + oa[mf][kf]);
#pragma unroll
                for (int nf = 0; nf < 4; ++nf)
                    acc[mf][nf] = MFMAH(vah, vbh[nf], acc[mf][nf]);
            }
        }
        __syncthreads();
    }

#pragma unroll
    for (int mf = 0; mf < 4; ++mf)
#pragma unroll
        for (int nf = 0; nf < 4; ++nf) {
            f32x4 v = acc[mf][nf];
            int col  = n0 + wc * 64 + nf * 16 + (lane & 15);
            int rowb = m0 + wr * 64 + mf * 16 + ((lane >> 4) << 2);
#pragma unroll
            for (int r = 0; r < 4; ++r) {
                long o = (zLo * 256 + rowb + r) * ldbias + 64 + col + zHi * hsA;
                v[r] += h2f(biasH[o]);
            }
#pragma unroll
            for (int r = 0; r < 4; ++r)
                Sf[zLo * sCf + zHi * hsC + (long)(rowb + r) * ldcf + col] = f2h(v[r]);
        }
}

// ================= 128x64 fp16 MFMA GEMM (small-N ops) =================
// BMODE: 0 none; 1 bias=biasF[zLo*hsBias+(64+t)*ldbias+col]; 3 OutU Wo pos fold
// BJUMP: B pointer jumps to head1 (UT stride 1048576) after k-tile 192.
template <int BMODE, bool KCAUSAL, bool ACC, bool OUTU, bool BJUMP>
__global__ __launch_bounds__(256) void gemm_mfma(
    const short* Ah, int lda, long sA,
    const short* Bh, int ldb, long sB, long hsB,
    float* Cf, int ldcf, long sCf,
    short* Chi, int ldch, long sCh,
    const float* biasF, long ldbias, long hsBias,
    long hsA, long hsC,
    short* UThi,
    int K)
{
    int m0 = blockIdx.y * 128, n0 = blockIdx.x * 64;
    long zLo = blockIdx.z & 63, zHi = blockIdx.z >> 6;
    const short* pAh = Ah + zLo * sA + zHi * hsA;
    const short* pBh = Bh + zLo * sB + zHi * hsB;

    __shared__ short lds[12288]; // LAh 8192 | LBh 4096
    short* LAh = lds;
    short* LBh = lds + 8192;

    int tid = threadIdx.x;
    int lane = tid & 63, w = tid >> 6;
    int wr = w >> 1, wc = w & 1;

    const short* aSH[4]; const short* bSH[2];
    int aLo[4], bLo[2];
#pragma unroll
    for (int j = 0; j < 4; ++j) {
        int o = j * 4096 + tid * 16;
        int c = swz(o); int r = c >> 7, col = (c & 127) >> 1;
        aSH[j] = pAh + (long)(m0 + r) * lda + col;
        aLo[j] = o >> 1;
    }
#pragma unroll
    for (int j = 0; j < 2; ++j) {
        int o = j * 4096 + tid * 16;
        int c = swz(o); int r = c >> 7, col = (c & 127) >> 1;
        bSH[j] = pBh + (long)(n0 + r) * ldb + col;
        bLo[j] = o >> 1;
    }

    int oa[4][2], ob[2][2];
#pragma unroll
    for (int mf = 0; mf < 4; ++mf)
#pragma unroll
        for (int kf = 0; kf < 2; ++kf) {
            int row = wr * 64 + mf * 16 + (lane & 15);
            oa[mf][kf] = swz(row * 128 + (kf * 32 + ((lane >> 4) << 3)) * 2) >> 1;
        }
#pragma unroll
    for (int nf = 0; nf < 2; ++nf)
#pragma unroll
        for (int kf = 0; kf < 2; ++kf) {
            int row = wc * 32 + nf * 16 + (lane & 15);
            ob[nf][kf] = swz(row * 128 + (kf * 32 + ((lane >> 4) << 3)) * 2) >> 1;
        }

    f32x4 acc[4][2] = {};
    int Klim = KCAUSAL ? (K < m0 + 128 ? K : m0 + 128) : K;

    for (int k0 = 0; k0 < Klim; k0 += 64) {
#pragma unroll
        for (int j = 0; j < 4; ++j) {
            GLOAD16(aSH[j], LAh + aLo[j]);
            aSH[j] += 64;
        }
        long bstep = (BJUMP && k0 == 192) ? (1048576L - 192L) : 64L;
#pragma unroll
        for (int j = 0; j < 2; ++j) {
            GLOAD16(bSH[j], LBh + bLo[j]);
            bSH[j] += bstep;
        }
        __syncthreads();
#pragma unroll
        for (int kf = 0; kf < 2; ++kf) {
            f16x8 vbh[2];
#pragma unroll
            for (int nf = 0; nf < 2; ++nf)
                vbh[nf] = *(const f16x8*)(LBh + ob[nf][kf]);
#pragma unroll
            for (int mf = 0; mf < 4; ++mf) {
                f16x8 vah = *(const f16x8*)(LAh + oa[mf][kf]);
#pragma unroll
                for (int nf = 0; nf < 2; ++nf)
                    acc[mf][nf] = MFMAH(vah, vbh[nf], acc[mf][nf]);
            }
        }
        __syncthreads();
    }

#pragma unroll
    for (int mf = 0; mf < 4; ++mf)
#pragma unroll
        for (int nf = 0; nf < 2; ++nf) {
            f32x4 v = acc[mf][nf];
            int col  = n0 + wc * 32 + nf * 16 + (lane & 15);
            int rowb = m0 + wr * 64 + mf * 16 + ((lane >> 4) << 2);
            if (BMODE == 1) {
#pragma unroll
                for (int r = 0; r < 4; ++r) {
                    int t = (rowb + r) & 255;
                    v[r] += biasF[zLo * hsBias + (long)(64 + t) * ldbias + col];
                }
            } else if (BMODE == 3) {
#pragma unroll
                for (int r = 0; r < 4; ++r) {
                    int t = (rowb + r) & 255;
                    v[r] += biasF[(long)(col - n0) * 2880 + (n0 >> 6) * 960 + 64 + t];
                }
            }
            if (OUTU) {
                if (n0 == 0) {
#pragma unroll
                    for (int r = 0; r < 4; ++r)
                        Cf[(long)(rowb + r) * ldcf + col] = v[r];
                } else {
                    int head = (n0 >> 6) - 1;
                    int o = col - n0;
                    short hs[4];
#pragma unroll
                    for (int r = 0; r < 4; ++r) hs[r] = f2h(v[r]);
                    short4v th = {hs[0], hs[1], hs[2], hs[3]};
                    *(short4v*)(UThi + head * 1048576L + (long)o * 16384 + rowb) = th;
                }
            } else if (ACC) {
#pragma unroll
                for (int r = 0; r < 4; ++r)
                    Cf[zLo * sCf + (long)(rowb + r) * ldcf + col] += v[r];
            } else if (Cf) {
#pragma unroll
                for (int r = 0; r < 4; ++r)
                    Cf[zLo * sCf + (long)(rowb + r) * ldcf + col] = v[r];
            } else {
#pragma unroll
                for (int r = 0; r < 4; ++r)
                    Chi[zHi * hsC + zLo * sCh + (long)(rowb + r) * ldch + col] = f2h(v[r]);
            }
        }
}

// ================= merged prep builds =================
// blocks [0,4096): hc x-cols; [4096,5120): hT; [5120,5648): Wf; [5648,5688): At0;
// [5688,7008): At1 compact-K transpose ([1920][704], 22 k0 x 30 n0 x 2 z)
__global__ __launch_bounds__(256) void build_all(const float* __restrict__ x,
                                                 const float* __restrict__ Wo,
                                                 const float* __restrict__ A0,
                                                 const float* __restrict__ A1,
                                                 short* __restrict__ hc,
                                                 short* __restrict__ hT,
                                                 short* __restrict__ Wf,
                                                 short* __restrict__ At0,
                                                 short* __restrict__ At1) {
    __shared__ float tile[32][33];
    int blk = blockIdx.x;
    int tid = threadIdx.x;
    if (blk < 4096) {
        int idx = blk * 256 + tid;
        int bt = idx >> 6, c = idx & 63;
        hc[(long)bt * DC + c] = f2h(x[(long)bt * NS + c]);
    } else if (blk < 5120) {
        int i = blk - 4096;
        int c0 = (i & 1) * 32, t0 = ((i >> 1) & 7) * 32, b = i >> 4;
        int tx = tid & 31, ty = tid >> 5;
        const float* xb = x + (long)b * NT * NS;
#pragma unroll
        for (int ii = ty; ii < 32; ii += 8) tile[ii][tx] = xb[(long)(t0 + ii) * NS + c0 + tx];
        __syncthreads();
        long base = (long)b * (NS * 256);
#pragma unroll
        for (int ii = ty; ii < 32; ii += 8)
            hT[base + (long)(c0 + ii) * 256 + t0 + tx] = f2h(tile[tx][ii]);
    } else if (blk < 5648) {
        int idx = (blk - 5120) * 256 + tid;
        if (idx < 192 * DC) {
            int r = idx / DC, kc = idx - r * DC;
            int o = r & 63, chunk = r >> 6;
            int srck = (kc < 64) ? kc : kc + 256;
            Wf[idx] = f2h(Wo[(long)o * ND2 + chunk * 960 + srck]);
        }
    } else if (blk < 5688) {
        int i = blk - 5648;                   // 40 = 2 k0 x 10 n0 x 2 z
        int k0 = (i & 1) * 32;
        int n0 = ((i >> 1) % 10) * 32;
        int z  = i / 20;
        int tx = tid & 31, ty = tid >> 5;
        long hbase = (long)z * ND0 * ND0;
#pragma unroll
        for (int ii = ty; ii < 32; ii += 8)
            tile[ii][tx] = A0[hbase + (long)(k0 + ii) * ND0 + n0 + tx];
        __syncthreads();
        long obase = (long)z * ND0 * 64;
#pragma unroll
        for (int ii = ty; ii < 32; ii += 8)
            At0[obase + (long)(n0 + ii) * 64 + k0 + tx] = f2h(tile[tx][ii]);
    } else {
        int i = blk - 5688;                   // 1320 = 22 k0 x 30 n0 x 2 z
        int k0 = (i % 22) * 32;
        int n0 = ((i / 22) % 30) * 32;
        int z  = i / 660;
        int tx = tid & 31, ty = tid >> 5;
        long hbase = (long)z * ND1 * ND1;
#pragma unroll
        for (int ii = ty; ii < 32; ii += 8) {
            int k = k0 + ii;
            int srck = (k < 64) ? k : k + 256;
            tile[ii][tx] = A1[hbase + (long)srck * ND1 + n0 + tx];
        }
        __syncthreads();
        long obase = (long)z * 960 * DC;
#pragma unroll
        for (int ii = ty; ii < 32; ii += 8)
            At1[obase + (long)(n0 + ii) * DC + k0 + tx] = f2h(tile[tx][ii]);
    }
}

// causal softmax: fp16 S in, merged heads (row>>14 = head), writes P fp16
__global__ __launch_bounds__(256) void softmax_split(const short* S,
                                                     short* pHi,
                                                     int ldo, long hs) {
    int row  = blockIdx.x * 4 + (threadIdx.x >> 6);
    int t    = row & (NT - 1);
    int hrow = row & 16383;
    int head = row >> 14;
    int lane = threadIdx.x & 63;
    int s0   = lane << 2;
    const short* p = S + (long)row * NT;

    short4v sv = *(const short4v*)(p + s0);
    float vv[4] = {h2f(sv[0]), h2f(sv[1]), h2f(sv[2]), h2f(sv[3])};
    float mx = -INFINITY;
#pragma unroll
    for (int j = 0; j < 4; ++j)
        if (s0 + j <= t) mx = fmaxf(mx, vv[j]);
    for (int off = 32; off; off >>= 1) mx = fmaxf(mx, __shfl_down(mx, off));
    mx = __shfl(mx, 0);

    float e[4]; float sum = 0.f;
#pragma unroll
    for (int j = 0; j < 4; ++j) {
        e[j] = (s0 + j <= t) ? __expf(vv[j] - mx) : 0.f;
        sum += e[j];
    }
    for (int off = 32; off; off >>= 1) sum += __shfl_down(sum, off);
    sum = __shfl(sum, 0);
    float inv = 1.f / sum;

    short hsv[4];
#pragma unroll
    for (int j = 0; j < 4; ++j) hsv[j] = f2h(e[j] * inv);
    short4v hv = {hsv[0], hsv[1], hsv[2], hsv[3]};
    *(short4v*)(pHi + (long)head * hs + (long)hrow * ldo + s0) = hv;
}

// ================= fp32 fallback (round-1, known-good) =================
__global__ __launch_bounds__(256) void build_h0(const float* __restrict__ x,
                                                float* __restrict__ h) {
    int idx = blockIdx.x * 256 + threadIdx.x;
    int bt = idx / ND0;
    int c  = idx - bt * ND0;
    int t  = bt & (NT - 1);
    float v;
    if (c < NS) v = x[(long)bt * NS + c];
    else        v = ((c - NS) == t) ? 1.0f : 0.0f;
    h[(long)bt * ND2 + c] = v;
}

template <bool BT, bool CAUSAL>
__global__ __launch_bounds__(256) void gemm64(
    const float* __restrict__ A, int lda, long sA,
    const float* __restrict__ Bm, int ldb, long sB,
    float* __restrict__ C, int ldc, long sC, int K)
{
    int m0 = blockIdx.y * 64, n0 = blockIdx.x * 64;
    if (CAUSAL && n0 > m0 + 63) return;
    long z = blockIdx.z;
    A += z * sA; Bm += z * sB; C += z * sC;

    __shared__ float As[16][68];
    __shared__ float Bs[16][68];

    int tid = threadIdx.x;
    int tx = tid & 15, ty = tid >> 4;
    int rowA = tid >> 2, kA = (tid & 3) << 2;
    int kB = tid >> 4,  colB = (tid & 15) << 2;

    float acc[4][4] = {};

    for (int k0 = 0; k0 < K; k0 += 16) {
        float4 av = *(const float4*)(A + (long)(m0 + rowA) * lda + k0 + kA);
        As[kA + 0][rowA] = av.x; As[kA + 1][rowA] = av.y;
        As[kA + 2][rowA] = av.z; As[kA + 3][rowA] = av.w;
        if (BT) {
            float4 bv = *(const float4*)(Bm + (long)(n0 + rowA) * ldb + k0 + kA);
            Bs[kA + 0][rowA] = bv.x; Bs[kA + 1][rowA] = bv.y;
            Bs[kA + 2][rowA] = bv.z; Bs[kA + 3][rowA] = bv.w;
        } else {
            float4 bv = *(const float4*)(Bm + (long)(k0 + kB) * ldb + n0 + colB);
            *(float4*)(&Bs[kB][colB]) = bv;
        }
        __syncthreads();
#pragma unroll
        for (int kk = 0; kk < 16; ++kk) {
            float4 a4 = *(const float4*)(&As[kk][ty << 2]);
            float4 b4 = *(const float4*)(&Bs[kk][tx << 2]);
            float a[4] = {a4.x, a4.y, a4.z, a4.w};
            float b[4] = {b4.x, b4.y, b4.z, b4.w};
#pragma unroll
            for (int i = 0; i < 4; ++i)
#pragma unroll
                for (int j = 0; j < 4; ++j)
                    acc[i][j] += a[i] * b[j];
        }
        __syncthreads();
    }
#pragma unroll
    for (int i = 0; i < 4; ++i) {
        float4 v = {acc[i][0], acc[i][1], acc[i][2], acc[i][3]};
        *(float4*)(C + (long)(m0 + (ty << 2) + i) * ldc + n0 + (tx << 2)) = v;
    }
}

__global__ __launch_bounds__(256) void softmax_causal(float* __restrict__ P) {
    int row  = blockIdx.x * 4 + (threadIdx.x >> 6);
    int t    = row & (NT - 1);
    int lane = threadIdx.x & 63;
    int s0   = lane << 2;
    float* p = P + (long)row * NT;

    float4 v = *(const float4*)(p + s0);
    float vv[4] = {v.x, v.y, v.z, v.w};
    float mx = -INFINITY;
#pragma unroll
    for (int j = 0; j < 4; ++j)
        if (s0 + j <= t) mx = fmaxf(mx, vv[j]);
    for (int off = 32; off; off >>= 1) mx = fmaxf(mx, __shfl_down(mx, off));
    mx = __shfl(mx, 0);

    float e[4]; float sum = 0.f;
#pragma unroll
    for (int j = 0; j < 4; ++j) {
        e[j] = (s0 + j <= t) ? __expf(vv[j] - mx) : 0.f;
        sum += e[j];
    }
    for (int off = 32; off; off >>= 1) sum += __shfl_down(sum, off);
    sum = __shfl(sum, 0);
    float inv = 1.f / sum;
    float4 o = {e[0] * inv, e[1] * inv, e[2] * inv, e[3] * inv};
    *(float4*)(p + s0) = o;
}

// ================= launch =================
extern "C" void kernel_launch(void* const* d_in, const int* in_sizes, int n_in,
                              void* d_out, int out_size, void* d_ws, size_t ws_size,
                              hipStream_t stream) {
    const float* x  = (const float*)d_in[0];
    const float* A0 = (const float*)d_in[1];
    const float* A1 = (const float*)d_in[2];
    const float* Wo = (const float*)d_in[3];
    float* out = (float*)d_out;

    if (ws_size >= 180527104UL) {
        char* wsb = (char*)d_ws;
        short* hc_hi = (short*)(wsb);                    // [16384][704]
        short* G_hi  = (short*)(wsb + 46137344L);        // [16384][1920]
        short* S     = (short*)(wsb + 113246208L);       // [2][64][256][256] fp16
        short* P     = (short*)(wsb + 146800640L);       // [16384][512] both-head P
        short* hT_hi = (short*)(wsb + 163577856L);       // [64][64][256]
        short* At0_h = (short*)(wsb + 167772160L);       // [2][320][64]
        short* Wf_hi = (short*)(wsb + 170655744L);       // [192][704]
        short* UT_hi = (short*)(wsb + 170926080L);       // [2][64][16384]
        short* At1_h = (short*)(wsb + 175120384L);       // [1920][704], end 180527104

        // merged prep: hc x-cols, hT, Wf, At0, At1
        build_all<<<7008, 256, 0, stream>>>(x, Wo, A0, A1, hc_hi, hT_hi, Wf_hi, At0_h, At1_h);

        // -------- layer 0 (K=64 after pos-fold) --------
        // G0 = x @ A0^T + A0[64+t,:] -> G_hi [16384][640], both heads (z=2: zLo=head)
        gemm_mfma<1, false, false, false, false><<<dim3(5, 128, 2), 256, 0, stream>>>(
            hc_hi, DC, 0L,
            At0_h, 64, 20480L, 0L,
            nullptr, 0, 0L, G_hi, 640, 320L,
            A0, 320L, 102400L,
            0L, 0L,
            nullptr, 64);
        // S = G0_x @ x^T + G0[.,64+s]  causal, both heads (z=128), fp16 S
        gemm128<false><<<dim3(2, 2, 128), 256, 0, stream>>>(
            G_hi, 640, 163840L,
            hc_hi, DC, 180224L,
            S, NT, 65536L,
            G_hi, 640L,
            320L, 4194304L, 64);
        softmax_split<<<8192, 256, 0, stream>>>(S, hc_hi + 128, DC, 320L);
        // PV0: hc[., 64+head*320 ..] = P @ x  (both heads, z=128)
        gemm_mfma<0, true, false, false, false><<<dim3(1, 2, 128), 256, 0, stream>>>(
            hc_hi + 128, DC, 180224L,
            hT_hi, 256, 16384L, 0L,
            nullptr, 0, 0L,
            hc_hi + 64, DC, 180224L,
            nullptr, 0L, 0L,
            320L, 320L,
            nullptr, 256);

        // -------- fused out-base + U heads (N=192) --------
        gemm_mfma<3, false, false, true, false><<<dim3(3, 128, 1), 256, 0, stream>>>(
            hc_hi, DC, 0L,
            Wf_hi, DC, 0L, 0L,
            out, NS, 0L, nullptr, 0, 0L,
            Wo, 0L, 0L,
            0L, 0L,
            UT_hi, DC);

        // -------- layer 1 --------
        // G1: 256x128 BK=64, N=1920, XCD swizzle (960 wgs)
        gemmG1<<<960, 256, 0, stream>>>(hc_hi, At1_h, G_hi, A1);
        // S = G1[compact] @ hc^T + G1[.,64+s]  causal, AJUMP, both heads (z=128), fp16 S
        gemm128<true><<<dim3(2, 2, 128), 256, 0, stream>>>(
            G_hi, 1920, 491520L,
            hc_hi, DC, 180224L,
            S, NT, 65536L,
            G_hi, 1920L,
            960L, 4194304L, DC);
        // P packed both heads per row: [16384][512], head offset 256
        softmax_split<<<8192, 256, 0, stream>>>(S, P, 512, 256L);
        // out += [P0|P1] @ [U0;U1]^T  (single dispatch, K=512, BJUMP at k=192->head1)
        gemm_mfma<0, false, true, false, true><<<dim3(1, 2, 64), 256, 0, stream>>>(
            P, 512, 131072L,
            UT_hi, 16384, 256L, 0L,
            out, NS, 16384L, nullptr, 0, 0L,
            nullptr, 0L, 0L,
            0L, 0L,
            nullptr, 512);
        return;
    }

    // ---------- fp32 fallback ----------
    float* ws = (float*)d_ws;
    float* h  = ws;
    float* G  = ws + 47185920L;
    float* Pf = ws + 47185920L + 15728640L;

    build_h0<<<(NB * NT * ND0) / 256, 256, 0, stream>>>(x, h);

    for (int layer = 0; layer < 2; ++layer) {
        int d = layer ? ND1 : ND0;
        const float* Am = layer ? A1 : A0;
        for (int head = 0; head < NH; ++head) {
            const float* Ah = Am + (long)head * d * d;
            gemm64<false, false><<<dim3(d / 64, 256, 1), 256, 0, stream>>>(
                h, ND2, 0L, Ah, d, 0L, G, d, 0L, d);
            gemm64<true, true><<<dim3(4, 4, NB), 256, 0, stream>>>(
                G, d, (long)NT * d, h, ND2, (long)NT * ND2,
                Pf, NT, (long)NT * NT, d);
            softmax_causal<<<(NB * NT) / 4, 256, 0, stream>>>(Pf);
            gemm64<false, false><<<dim3(d / 64, 4, NB), 256, 0, stream>>>(
                Pf, NT, (long)NT * NT, h, ND2, (long)NT * ND2,
                h + (long)d * (1 + head), ND2, (long)NT * ND2, NT);
        }
    }
    gemm64<true, false><<<dim3(1, 256, 1), 256, 0, stream>>>(
        h, ND2, 0L, Wo, ND2, 0L, out, NS, 0L, ND2);
}